// Round 3
// baseline (6599.094 us; speedup 1.0000x reference)
//
#include <hip/hip_runtime.h>
#include <hip/hip_bf16.h>
#include <cstddef>

// Problem dims
#define TT 256
#define BB 64
#define NN 77
#define DD 512
#define SS 334            // T + N + 1
#define HH 8
#define M1 (SS*BB)        // 21376
#define M2 (BB*TT)        // 16384
#define FFSA 1024
#define FF 2048

// Workspace: 3 regions of 10,944,512 floats each (total 125.25 MiB).
// Region A (ws + 0):      src -> xn -> {tn,kc,vc,ctx} -> yb/hst -> ffmid_q
// Region B (ws + REG):    qkv_h / proj / proj2 -> qc -> y2/hst2 ; smalls at +8.39M
// Region C (ws + 2*REG):  o / ff1_half -> xb
#define REG 10944512ULL

// ---------------- concat [x; xf; emb] -> src ----------------
__global__ __launch_bounds__(256) void concat_src_kernel(
    const float* __restrict__ x, const float* __restrict__ xf,
    const float* __restrict__ emb, float* __restrict__ src) {
  int idx = blockIdx.x * 256 + threadIdx.x;      // float4 index
  if (idx >= SS * BB * 128) return;
  int c4 = idx & 127;
  int row = idx >> 7;                            // s*BB + b
  int s = row >> 6, b = row & 63;
  const float* p;
  if (s < TT)            p = x   + ((size_t)(s * BB + b)) * DD;
  else if (s < TT + NN)  p = xf  + ((size_t)((s - TT) * BB + b)) * DD;
  else                   p = emb + (size_t)b * DD;
  ((float4*)(src + (size_t)row * DD))[c4] = ((const float4*)p)[c4];
}

// ---------------- generic GEMM: C = epi(A[M,K] @ W[N,K]^T + bias) -----
// EPI: 0 none, 1 relu, 2 gelu(exact), 3 add-into-C
template<int EPI>
__global__ __launch_bounds__(256) void gemm_tn(
    const float* __restrict__ A, const float* __restrict__ W,
    const float* __restrict__ bias, float* __restrict__ C,
    int M, int N, int K, int ldc) {
  __shared__ float As[16][64];
  __shared__ float Ws[16][64];
  const int tid = threadIdx.x;
  const int bm = blockIdx.y << 6;
  const int bn = blockIdx.x << 6;
  const int lr = tid >> 2;            // 0..63
  const int lk = (tid & 3) << 2;      // 0,4,8,12
  const float* Ap = A + (size_t)(bm + lr) * K + lk;
  const float* Wp = W + (size_t)(bn + lr) * K + lk;
  const int tx = tid & 15, ty = tid >> 4;
  float c[4][4] = {};
  for (int k0 = 0; k0 < K; k0 += 16) {
    float4 av = *(const float4*)(Ap + k0);
    float4 wv = *(const float4*)(Wp + k0);
    __syncthreads();
    As[lk + 0][lr] = av.x; As[lk + 1][lr] = av.y;
    As[lk + 2][lr] = av.z; As[lk + 3][lr] = av.w;
    Ws[lk + 0][lr] = wv.x; Ws[lk + 1][lr] = wv.y;
    Ws[lk + 2][lr] = wv.z; Ws[lk + 3][lr] = wv.w;
    __syncthreads();
#pragma unroll
    for (int k = 0; k < 16; ++k) {
      const float4 a = *(const float4*)&As[k][ty << 2];
      const float4 w = *(const float4*)&Ws[k][tx << 2];
      c[0][0] += a.x * w.x; c[0][1] += a.x * w.y; c[0][2] += a.x * w.z; c[0][3] += a.x * w.w;
      c[1][0] += a.y * w.x; c[1][1] += a.y * w.y; c[1][2] += a.y * w.z; c[1][3] += a.y * w.w;
      c[2][0] += a.z * w.x; c[2][1] += a.z * w.y; c[2][2] += a.z * w.z; c[2][3] += a.z * w.w;
      c[3][0] += a.w * w.x; c[3][1] += a.w * w.y; c[3][2] += a.w * w.z; c[3][3] += a.w * w.w;
    }
  }
#pragma unroll
  for (int i = 0; i < 4; ++i) {
    int row = bm + (ty << 2) + i;
    float* Cp = C + (size_t)row * ldc + bn + (tx << 2);
#pragma unroll
    for (int j = 0; j < 4; ++j) {
      float v = c[i][j] + bias[bn + (tx << 2) + j];
      if (EPI == 1) v = fmaxf(v, 0.f);
      if (EPI == 2) v = 0.5f * v * (1.f + erff(v * 0.70710678118f));
      if (EPI == 3) Cp[j] += v; else Cp[j] = v;
    }
  }
}

// ---------------- self-attention for ONE head, qkvh [M1,192] -----------
// cols: q at 0, k at 64, v at 128. oh points at o + h*64 (row stride 512).
__global__ __launch_bounds__(256) void attn_head_kernel(
    const float* __restrict__ qkvh, float* __restrict__ oh) {
  __shared__ float qs[16][64];
  __shared__ float sc[16][336];
  int b = blockIdx.y;
  int s0 = blockIdx.x << 4;
  int tid = threadIdx.x;
  for (int l = tid; l < 1024; l += 256) {
    int i = l >> 6, d = l & 63;
    int s = s0 + i;
    float qv = 0.f;
    if (s < SS) qv = qkvh[((size_t)(s * BB + b)) * 192 + d] * 0.125f;
    qs[i][d] = qv;
  }
  __syncthreads();
  int i = tid >> 4, jt = tid & 15;
  for (int t = jt; t < SS; t += 16) {
    const float* kp = qkvh + ((size_t)(t * BB + b)) * 192 + 64;
    float acc = 0.f;
#pragma unroll
    for (int d = 0; d < 64; ++d) acc += qs[i][d] * kp[d];
    sc[i][t] = acc;
  }
  __syncthreads();
  float m = -1e30f;
  for (int t = jt; t < SS; t += 16) m = fmaxf(m, sc[i][t]);
#pragma unroll
  for (int off = 8; off; off >>= 1) m = fmaxf(m, __shfl_xor(m, off, 16));
  float sum = 0.f;
  for (int t = jt; t < SS; t += 16) { float e = __expf(sc[i][t] - m); sc[i][t] = e; sum += e; }
#pragma unroll
  for (int off = 8; off; off >>= 1) sum += __shfl_xor(sum, off, 16);
  float inv = 1.f / sum;
  __syncthreads();
  float a0 = 0, a1 = 0, a2 = 0, a3 = 0;
  for (int t = 0; t < SS; ++t) {
    float p = sc[i][t];
    const float* vp = qkvh + ((size_t)(t * BB + b)) * 192 + 128 + (jt << 2);
    a0 += p * vp[0]; a1 += p * vp[1]; a2 += p * vp[2]; a3 += p * vp[3];
  }
  int s = s0 + i;
  if (s < SS) {
    float* op = oh + ((size_t)(s * BB + b)) * DD + (jt << 2);
    op[0] = a0 * inv; op[1] = a1 * inv; op[2] = a2 * inv; op[3] = a3 * inv;
  }
}

// ---------------- LayerNorm row kernel (D=512, 1 wave/row) -------------
__global__ __launch_bounds__(64) void ln_kernel(
    const float* __restrict__ in, const float* __restrict__ res,
    float* __restrict__ out, const float* __restrict__ g,
    const float* __restrict__ beta) {
  const int row = blockIdx.x;
  const int lane = threadIdx.x;
  const float* ip = in + (size_t)row * DD;
  float v[8];
  float s = 0.f, ss = 0.f;
#pragma unroll
  for (int u = 0; u < 2; ++u) {
    int d = u * 256 + lane * 4;
    float4 a = *(const float4*)(ip + d);
    if (res) {
      float4 r = *(const float4*)(res + (size_t)row * DD + d);
      a.x += r.x; a.y += r.y; a.z += r.z; a.w += r.w;
    }
    v[u * 4 + 0] = a.x; v[u * 4 + 1] = a.y; v[u * 4 + 2] = a.z; v[u * 4 + 3] = a.w;
    s += a.x + a.y + a.z + a.w;
    ss += a.x * a.x + a.y * a.y + a.z * a.z + a.w * a.w;
  }
#pragma unroll
  for (int off = 32; off; off >>= 1) { s += __shfl_xor(s, off); ss += __shfl_xor(ss, off); }
  float mean = s * (1.f / 512.f);
  float var = ss * (1.f / 512.f) - mean * mean;
  float rstd = rsqrtf(var + 1e-5f);
  float* op = out + (size_t)row * DD;
#pragma unroll
  for (int u = 0; u < 2; ++u) {
    int d = u * 256 + lane * 4;
    float4 o4;
    o4.x = (v[u * 4 + 0] - mean) * rstd * g[d + 0] + beta[d + 0];
    o4.y = (v[u * 4 + 1] - mean) * rstd * g[d + 1] + beta[d + 1];
    o4.z = (v[u * 4 + 2] - mean) * rstd * g[d + 2] + beta[d + 2];
    o4.w = (v[u * 4 + 3] - mean) * rstd * g[d + 3] + beta[d + 3];
    *(float4*)(op + d) = o4;
  }
}

// ---------------- stylization inner: silu(LN(y)*(1+scale)+shift) -------
// out may alias y (row-local).
__global__ __launch_bounds__(64) void styl_kernel(
    const float* __restrict__ y, const float* __restrict__ eo,
    const float* __restrict__ g, const float* __restrict__ beta,
    float* __restrict__ out) {
  const int row = blockIdx.x;         // b*TT + t
  const int b = row >> 8;
  const int lane = threadIdx.x;
  const float* ip = y + (size_t)row * DD;
  const float* sc = eo + (size_t)b * 1024;
  float v[8];
  float s = 0.f, ss = 0.f;
#pragma unroll
  for (int u = 0; u < 2; ++u) {
    int d = u * 256 + lane * 4;
    float4 a = *(const float4*)(ip + d);
    v[u * 4 + 0] = a.x; v[u * 4 + 1] = a.y; v[u * 4 + 2] = a.z; v[u * 4 + 3] = a.w;
    s += a.x + a.y + a.z + a.w;
    ss += a.x * a.x + a.y * a.y + a.z * a.z + a.w * a.w;
  }
#pragma unroll
  for (int off = 32; off; off >>= 1) { s += __shfl_xor(s, off); ss += __shfl_xor(ss, off); }
  float mean = s * (1.f / 512.f);
  float var = ss * (1.f / 512.f) - mean * mean;
  float rstd = rsqrtf(var + 1e-5f);
  float* op = out + (size_t)row * DD;
#pragma unroll
  for (int u = 0; u < 2; ++u) {
    int d0 = u * 256 + lane * 4;
#pragma unroll
    for (int j = 0; j < 4; ++j) {
      int d = d0 + j;
      float ln = (v[u * 4 + j] - mean) * rstd * g[d] + beta[d];
      float h = ln * (1.f + sc[d]) + sc[512 + d];
      op[d] = h / (1.f + __expf(-h));
    }
  }
}

// ---------------- per-64-group softmax (qc, last axis) -----------------
__global__ __launch_bounds__(512) void softmax64_kernel(float* __restrict__ a) {
  int row = blockIdx.x;
  int lane = threadIdx.x & 63;
  int h = threadIdx.x >> 6;
  float* p = a + (size_t)row * DD + h * 64;
  float v = p[lane];
  float m = v;
#pragma unroll
  for (int off = 32; off; off >>= 1) m = fmaxf(m, __shfl_xor(m, off));
  float e = __expf(v - m);
  float sum = e;
#pragma unroll
  for (int off = 32; off; off >>= 1) sum += __shfl_xor(sum, off);
  p[lane] = e / sum;
}

// ---------------- softmax over n (kc, axis=1, 77 tokens) ---------------
__global__ __launch_bounds__(256) void softmax_n_kernel(float* __restrict__ a) {
  int b = blockIdx.x;
  int c = blockIdx.y * 256 + threadIdx.x;     // 0..511
  float* p = a + ((size_t)b * NN) * DD + c;
  float m = -1e30f;
  for (int n = 0; n < NN; ++n) m = fmaxf(m, p[(size_t)n * DD]);
  float sum = 0.f;
  for (int n = 0; n < NN; ++n) sum += __expf(p[(size_t)n * DD] - m);
  float inv = 1.f / sum;
  for (int n = 0; n < NN; ++n) p[(size_t)n * DD] = __expf(p[(size_t)n * DD] - m) * inv;
}

// ---------------- ctx[b,h,d,l] = sum_n kc[b,n,h,d]*vc[b,n,h,l] ---------
__global__ __launch_bounds__(256) void ctx_kernel(
    const float* __restrict__ kc, const float* __restrict__ vc,
    float* __restrict__ ctx) {
  __shared__ float ks[NN][64];
  __shared__ float vs[NN][64];
  int bh = blockIdx.x; int b = bh >> 3, h = bh & 7;
  for (int l = threadIdx.x; l < NN * 64; l += 256) {
    int n = l >> 6, d = l & 63;
    size_t idx = ((size_t)(b * NN + n)) * DD + h * 64 + d;
    ks[n][d] = kc[idx];
    vs[n][d] = vc[idx];
  }
  __syncthreads();
  int d = threadIdx.x >> 2;
  int l0 = (threadIdx.x & 3) << 4;
  float acc[16] = {};
  for (int n = 0; n < NN; ++n) {
    float kd = ks[n][d];
#pragma unroll
    for (int j = 0; j < 16; ++j) acc[j] += kd * vs[n][l0 + j];
  }
  float* cp = ctx + ((size_t)bh * 64 + d) * 64 + l0;
#pragma unroll
  for (int j = 0; j < 16; ++j) cp[j] = acc[j];
}

// ---------------- y[b,t,h,l] = sum_d qc[b,t,h,d]*ctx[b,h,d,l] ----------
__global__ __launch_bounds__(256) void lin_y_kernel(
    const float* __restrict__ qc, const float* __restrict__ ctx,
    float* __restrict__ y) {
  __shared__ float cs[64][64];
  int bh = blockIdx.x; int b = bh >> 3, h = bh & 7;
  for (int l = threadIdx.x; l < 4096; l += 256)
    cs[l >> 6][l & 63] = ctx[(size_t)bh * 4096 + l];
  __syncthreads();
  int tg = threadIdx.x >> 6, l = threadIdx.x & 63;
  for (int t = tg * 64; t < tg * 64 + 64; ++t) {
    const float* qp = qc + ((size_t)(b * TT + t)) * DD + h * 64;
    float acc = 0.f;
#pragma unroll
    for (int d2 = 0; d2 < 64; ++d2) acc += qp[d2] * cs[d2][l];
    y[((size_t)(b * TT + t)) * DD + h * 64 + l] = acc;
  }
}

// ---------------- silu elementwise ------------------------------------
__global__ __launch_bounds__(256) void silu_kernel(
    const float* __restrict__ in, float* __restrict__ out, int n) {
  int i = blockIdx.x * 256 + threadIdx.x;
  if (i < n) { float v = in[i]; out[i] = v / (1.f + __expf(-v)); }
}

// ---------------- transposes ------------------------------------------
__global__ __launch_bounds__(256) void t2b_kernel(
    const float* __restrict__ srcm, float* __restrict__ dst, int R1) {
  int idx = blockIdx.x * 256 + threadIdx.x;
  if (idx >= R1 * BB * 128) return;
  int c4 = idx & 127;
  int row = idx >> 7;                  // b*R1 + r
  int b = row / R1, r = row % R1;
  ((float4*)(dst + (size_t)row * DD))[c4] =
      ((const float4*)(srcm + ((size_t)(r * BB + b)) * DD))[c4];
}
__global__ __launch_bounds__(256) void b2t_kernel(
    const float* __restrict__ xb, float* __restrict__ out) {
  int idx = blockIdx.x * 256 + threadIdx.x;
  if (idx >= TT * BB * 128) return;
  int c4 = idx & 127;
  int row = idx >> 7;                  // t*BB + b
  int t = row >> 6, b = row & 63;
  ((float4*)(out + (size_t)row * DD))[c4] =
      ((const float4*)(xb + ((size_t)(b * TT + t)) * DD))[c4];
}

extern "C" void kernel_launch(void* const* d_in, const int* in_sizes, int n_in,
                              void* d_out, int out_size, void* d_ws, size_t ws_size,
                              hipStream_t stream) {
  const float* x       = (const float*)d_in[0];
  const float* xf      = (const float*)d_in[1];
  const float* emb     = (const float*)d_in[2];
  const float* sa_in_w = (const float*)d_in[3];
  const float* sa_in_b = (const float*)d_in[4];
  const float* sa_out_w= (const float*)d_in[5];
  const float* sa_out_b= (const float*)d_in[6];
  const float* sa_l1_w = (const float*)d_in[7];
  const float* sa_l1_b = (const float*)d_in[8];
  const float* sa_l2_w = (const float*)d_in[9];
  const float* sa_l2_b = (const float*)d_in[10];
  const float* sa_n1_g = (const float*)d_in[11];
  const float* sa_n1_b = (const float*)d_in[12];
  const float* sa_n2_g = (const float*)d_in[13];
  const float* sa_n2_b = (const float*)d_in[14];
  const float* ca_norm_g = (const float*)d_in[15];
  const float* ca_norm_b = (const float*)d_in[16];
  const float* ca_tnorm_g= (const float*)d_in[17];
  const float* ca_tnorm_b= (const float*)d_in[18];
  const float* ca_q_w  = (const float*)d_in[19];
  const float* ca_q_b  = (const float*)d_in[20];
  const float* ca_k_w  = (const float*)d_in[21];
  const float* ca_k_b  = (const float*)d_in[22];
  const float* ca_v_w  = (const float*)d_in[23];
  const float* ca_v_b  = (const float*)d_in[24];
  const float* ca_se_w = (const float*)d_in[25];
  const float* ca_se_b = (const float*)d_in[26];
  const float* ca_sn_g = (const float*)d_in[27];
  const float* ca_sn_b = (const float*)d_in[28];
  const float* ca_so_w = (const float*)d_in[29];
  const float* ca_so_b = (const float*)d_in[30];
  const float* ff_l1_w = (const float*)d_in[31];
  const float* ff_l1_b = (const float*)d_in[32];
  const float* ff_l2_w = (const float*)d_in[33];
  const float* ff_l2_b = (const float*)d_in[34];
  const float* ff_se_w = (const float*)d_in[35];
  const float* ff_se_b = (const float*)d_in[36];
  const float* ff_sn_g = (const float*)d_in[37];
  const float* ff_sn_b = (const float*)d_in[38];
  const float* ff_so_w = (const float*)d_in[39];
  const float* ff_so_b = (const float*)d_in[40];

  float* A = (float*)d_ws;              // region A
  float* Bv = A + REG;                  // region B
  float* Cv = Bv + REG;                 // region C
  float* se  = Bv + 8388608;            // [64,512]   (region B slack)
  float* eo  = se + 32768;              // [64,1024]
  float* eo2 = eo + 65536;              // [64,1024]

  // ---------- Phase A: self-attention transformer block ----------
  concat_src_kernel<<<10688, 256, 0, stream>>>(x, xf, emb, A);   // src = A
  // per-head qkv + attention -> o (Cv)
  for (int h = 0; h < HH; ++h) {
    for (int sec = 0; sec < 3; ++sec) {
      gemm_tn<0><<<dim3(1, 334), 256, 0, stream>>>(
          A, sa_in_w + (size_t)(sec * 512 + h * 64) * DD,
          sa_in_b + sec * 512 + h * 64, Bv + sec * 64, M1, 64, DD, 192);
    }
    attn_head_kernel<<<dim3(21, BB), 256, 0, stream>>>(Bv, Cv + h * 64);
  }
  // proj = o @ sa_out_w^T + b  -> Bv
  gemm_tn<0><<<dim3(8, 334), 256, 0, stream>>>(Cv, sa_out_w, sa_out_b, Bv, M1, DD, DD, DD);
  // src = LN(src + proj)
  ln_kernel<<<M1, 64, 0, stream>>>(A, Bv, A, sa_n1_g, sa_n1_b);
  // FFN in two M-halves: ff1h -> Cv, proj2 -> Bv
  for (int half = 0; half < 2; ++half) {
    int m0 = half * 10688;
    gemm_tn<1><<<dim3(16, 167), 256, 0, stream>>>(
        A + (size_t)m0 * DD, sa_l1_w, sa_l1_b, Cv, 10688, FFSA, DD, FFSA);
    gemm_tn<0><<<dim3(8, 167), 256, 0, stream>>>(
        Cv, sa_l2_w, sa_l2_b, Bv + (size_t)m0 * DD, 10688, DD, FFSA, DD);
  }
  // src = LN(src + proj2)
  ln_kernel<<<M1, 64, 0, stream>>>(A, Bv, A, sa_n2_g, sa_n2_b);

  // ---------- Phase B: linear cross-attention + stylization ----------
  // xb = Cv ; xn = A (after src consumed) ; qc = Bv
  t2b_kernel<<<8192, 256, 0, stream>>>(A, Cv, TT);                  // xb
  ln_kernel<<<M2, 64, 0, stream>>>(Cv, nullptr, A, ca_norm_g, ca_norm_b);  // xn -> A
  gemm_tn<0><<<dim3(8, 256), 256, 0, stream>>>(A, ca_q_w, ca_q_b, Bv, M2, DD, DD, DD);
  softmax64_kernel<<<M2, 512, 0, stream>>>(Bv);                     // qc in-place
  // tn/kc/vc/ctx packed into region A (xn now dead)
  float* tn  = A;                        // [4928,512]
  float* kc  = A + 2523136;              // [4928,512]
  float* vc  = A + 5046272;              // [4928,512]
  float* ctx = A + 8388608;              // [512,64,64]
  t2b_kernel<<<2464, 256, 0, stream>>>(xf, tn, NN);
  ln_kernel<<<BB * NN, 64, 0, stream>>>(tn, nullptr, tn, ca_tnorm_g, ca_tnorm_b);
  gemm_tn<0><<<dim3(8, 77), 256, 0, stream>>>(tn, ca_k_w, ca_k_b, kc, BB * NN, DD, DD, DD);
  softmax_n_kernel<<<dim3(64, 2), 256, 0, stream>>>(kc);
  gemm_tn<0><<<dim3(8, 77), 256, 0, stream>>>(tn, ca_v_w, ca_v_b, vc, BB * NN, DD, DD, DD);
  ctx_kernel<<<BB * HH, 256, 0, stream>>>(kc, vc, ctx);
  // stylization scale/shift vectors (emb-only; compute both now)
  silu_kernel<<<128, 256, 0, stream>>>(emb, se, BB * DD);
  gemm_tn<0><<<dim3(16, 1), 256, 0, stream>>>(se, ca_se_w, ca_se_b, eo, BB, 1024, DD, 1024);
  gemm_tn<0><<<dim3(16, 1), 256, 0, stream>>>(se, ff_se_w, ff_se_b, eo2, BB, 1024, DD, 1024);
  // y = qc @ ctx -> A[0:8.39M] (tn/kc/vc dead) ; then styl in-place
  lin_y_kernel<<<BB * HH, 256, 0, stream>>>(Bv, ctx, A);
  styl_kernel<<<M2, 64, 0, stream>>>(A, eo, ca_sn_g, ca_sn_b, A);
  gemm_tn<3><<<dim3(8, 256), 256, 0, stream>>>(A, ca_so_w, ca_so_b, Cv, M2, DD, DD, DD);

  // ---------- Phase C: FFN + stylization (four M-quarters) ----------
  for (int q = 0; q < 4; ++q) {
    int m0 = q * 4096;
    gemm_tn<2><<<dim3(32, 64), 256, 0, stream>>>(
        Cv + (size_t)m0 * DD, ff_l1_w, ff_l1_b, A, 4096, FF, DD, FF);
    gemm_tn<0><<<dim3(8, 64), 256, 0, stream>>>(
        A, ff_l2_w, ff_l2_b, Bv + (size_t)m0 * DD, 4096, DD, FF, DD);
  }
  styl_kernel<<<M2, 64, 0, stream>>>(Bv, eo2, ff_sn_g, ff_sn_b, Bv);
  gemm_tn<3><<<dim3(8, 256), 256, 0, stream>>>(Bv, ff_so_w, ff_so_b, Cv, M2, DD, DD, DD);

  // ---------- output transpose ----------
  b2t_kernel<<<8192, 256, 0, stream>>>(Cv, (float*)d_out);
}

// Round 4
// 2289.438 us; speedup vs baseline: 2.8824x; 2.8824x over previous
//
#include <hip/hip_runtime.h>
#include <hip/hip_bf16.h>
#include <cstddef>

// Problem dims
#define TT 256
#define BB 64
#define NN 77
#define DD 512
#define SS 334            // T + N + 1
#define HH 8
#define M1 (SS*BB)        // 21376
#define M2 (BB*TT)        // 16384
#define FFSA 1024
#define FF 2048

// Workspace: 3 regions of 10,944,512 floats each (125.25 MiB total, proven OK).
// R1: src_f32 -> xn -> {kc,vc,ctx} -> y2
// R2: KV_bf -> proj -> h1_bf -> {y, smalls} -> g1_bf(half)
// R3: Q_bf+o_bf -> proj2 -> {xb, tn}
// d_out doubles as scratch: qc -> hst -> hst2 -> final output
#define REG 10944512ULL

typedef __attribute__((ext_vector_type(4))) float f32x4;
typedef __attribute__((ext_vector_type(8))) short bf16x8;
typedef __attribute__((ext_vector_type(8))) unsigned short u16x8;

__device__ inline unsigned short f2bf(float f) {
  __hip_bfloat16 h = __float2bfloat16(f);
  return *reinterpret_cast<unsigned short*>(&h);
}
__device__ inline float bf2f(unsigned short u) {
  return __uint_as_float(((unsigned)u) << 16);
}

// ---------------- concat [x; xf; emb] -> src (f32) ----------------
__global__ __launch_bounds__(256) void concat_src_kernel(
    const float* __restrict__ x, const float* __restrict__ xf,
    const float* __restrict__ emb, float* __restrict__ src) {
  int idx = blockIdx.x * 256 + threadIdx.x;      // float4 index
  if (idx >= SS * BB * 128) return;
  int c4 = idx & 127;
  int row = idx >> 7;                            // s*BB + b
  int s = row >> 6, b = row & 63;
  const float* p;
  if (s < TT)            p = x   + ((size_t)(s * BB + b)) * DD;
  else if (s < TT + NN)  p = xf  + ((size_t)((s - TT) * BB + b)) * DD;
  else                   p = emb + (size_t)b * DD;
  ((float4*)(src + (size_t)row * DD))[c4] = ((const float4*)p)[c4];
}

// ---------------- MFMA GEMM: C = epi(A[M,K] @ W[N,K]^T + bias) --------
// 128x128 tile, 4 waves (each 64x64), 16x16x32 bf16 MFMA, BK=32.
// A: f32 (ABF=false) or bf16 (ABF=true). W: f32, converted on the fly.
// EPI: 0 none, 1 relu, 2 gelu(exact), 3 add-into-C(f32)
// CBF: write bf16 (ushort) output instead of f32.
// N = gridDim.x*128 exactly; M may be ragged (guarded).
template<int EPI, bool ABF, bool CBF>
__global__ __launch_bounds__(256) void gemm_mfma(
    const void* __restrict__ Ap_, const float* __restrict__ W,
    const float* __restrict__ bias, void* __restrict__ Cp_,
    int M, int K, int ldc) {
  __shared__ unsigned short As[4][128][8];   // [k-chunk][row][k-in-chunk]
  __shared__ unsigned short Bs[4][128][8];
  const int tid = threadIdx.x;
  const int bm = blockIdx.y * 128;
  const int bn = blockIdx.x * 128;
  const int lane = tid & 63;
  const int wave = tid >> 6;
  const int wr = wave >> 1, wc = wave & 1;      // 2x2 wave grid of 64x64
  const int q = lane >> 4, lr = lane & 15;

  f32x4 acc[4][4];
#pragma unroll
  for (int m = 0; m < 4; ++m)
#pragma unroll
    for (int n = 0; n < 4; ++n) acc[m][n] = (f32x4){0.f, 0.f, 0.f, 0.f};

  // staging: thread -> row = tid>>1 (0..127), k-offset = (tid&1)*16
  const int srow = tid >> 1;
  const int skc = (tid & 1) * 16;
  int arow = bm + srow; if (arow >= M) arow = M - 1;
  const int brow = bn + srow;

  for (int k0 = 0; k0 < K; k0 += 32) {
    u16x8 av0, av1, bv0, bv1;
    if (ABF) {
      const unsigned short* Ar = (const unsigned short*)Ap_ + (size_t)arow * K + k0 + skc;
      av0 = *(const u16x8*)Ar;
      av1 = *(const u16x8*)(Ar + 8);
    } else {
      const float* Ar = (const float*)Ap_ + (size_t)arow * K + k0 + skc;
#pragma unroll
      for (int j = 0; j < 8; ++j) av0[j] = f2bf(Ar[j]);
#pragma unroll
      for (int j = 0; j < 8; ++j) av1[j] = f2bf(Ar[8 + j]);
    }
    {
      const float* Wr = W + (size_t)brow * K + k0 + skc;
#pragma unroll
      for (int j = 0; j < 8; ++j) bv0[j] = f2bf(Wr[j]);
#pragma unroll
      for (int j = 0; j < 8; ++j) bv1[j] = f2bf(Wr[8 + j]);
    }
    __syncthreads();   // previous iteration's fragment reads done
    const int c0 = skc >> 3;            // 0 or 2
    *(u16x8*)&As[c0][srow][0] = av0;
    *(u16x8*)&As[c0 + 1][srow][0] = av1;
    *(u16x8*)&Bs[c0][srow][0] = bv0;
    *(u16x8*)&Bs[c0 + 1][srow][0] = bv1;
    __syncthreads();
    bf16x8 af[4], bf[4];
#pragma unroll
    for (int m = 0; m < 4; ++m) af[m] = *(const bf16x8*)&As[q][wr * 64 + m * 16 + lr][0];
#pragma unroll
    for (int n = 0; n < 4; ++n) bf[n] = *(const bf16x8*)&Bs[q][wc * 64 + n * 16 + lr][0];
#pragma unroll
    for (int m = 0; m < 4; ++m)
#pragma unroll
      for (int n = 0; n < 4; ++n)
        acc[m][n] = __builtin_amdgcn_mfma_f32_16x16x32_bf16(af[m], bf[n], acc[m][n], 0, 0, 0);
  }

  // epilogue: D reg i of lane l -> row (l>>4)*4+i, col l&15 within 16x16 frag
#pragma unroll
  for (int m = 0; m < 4; ++m) {
#pragma unroll
    for (int n = 0; n < 4; ++n) {
      const int col = bn + wc * 64 + n * 16 + lr;
      const float bb = bias[col];
#pragma unroll
      for (int i = 0; i < 4; ++i) {
        const int row = bm + wr * 64 + m * 16 + q * 4 + i;
        if (row < M) {
          float v = acc[m][n][i] + bb;
          if (EPI == 1) v = fmaxf(v, 0.f);
          if (EPI == 2) v = 0.5f * v * (1.f + erff(v * 0.70710678118f));
          if (CBF) {
            ((unsigned short*)Cp_)[(size_t)row * ldc + col] = f2bf(v);
          } else {
            float* C = (float*)Cp_ + (size_t)row * ldc + col;
            if (EPI == 3) *C += v; else *C = v;
          }
        }
      }
    }
  }
}

// ---------------- self-attention, bf16 Q/KV in, bf16 O out -------------
// Q_bf [M1,512] (row s*BB+b, col h*64+d); KV_bf [M1,1024] (K at h*64, V at 512+h*64)
// grid (21, B*H); 256 threads; 16 queries per block.
__global__ __launch_bounds__(256) void attn2_kernel(
    const unsigned short* __restrict__ Qb, const unsigned short* __restrict__ KVb,
    unsigned short* __restrict__ Ob) {
  __shared__ float qs[16][64];
  __shared__ float kv[64][65];
  __shared__ float sc[16][384];
  const int bh = blockIdx.y, b = bh >> 3, h = bh & 7;
  const int s0 = blockIdx.x << 4;
  const int t = threadIdx.x;
  const int qi = t >> 4, l4 = t & 15;
  // Q tile -> LDS (scaled)
  {
    int c = l4 * 4;
    int s = s0 + qi;
    float4 q4 = {0.f, 0.f, 0.f, 0.f};
    if (s < SS) {
      ushort4 u = *(const ushort4*)(Qb + ((size_t)(s * BB + b)) * 512 + h * 64 + c);
      q4.x = bf2f(u.x) * 0.125f; q4.y = bf2f(u.y) * 0.125f;
      q4.z = bf2f(u.z) * 0.125f; q4.w = bf2f(u.w) * 0.125f;
    }
    qs[qi][c] = q4.x; qs[qi][c + 1] = q4.y; qs[qi][c + 2] = q4.z; qs[qi][c + 3] = q4.w;
  }
  const int sr = t >> 2, scc = (t & 3) * 16;   // staging row / col0
  // pass 1: scores
  for (int kt = 0; kt < 6; ++kt) {
    __syncthreads();
    {
      int sK = kt * 64 + sr;
      if (sK < SS) {
        const unsigned short* kp = KVb + ((size_t)(sK * BB + b)) * 1024 + h * 64 + scc;
#pragma unroll
        for (int j = 0; j < 4; ++j) {
          ushort4 u = *(const ushort4*)(kp + j * 4);
          kv[sr][scc + j * 4 + 0] = bf2f(u.x);
          kv[sr][scc + j * 4 + 1] = bf2f(u.y);
          kv[sr][scc + j * 4 + 2] = bf2f(u.z);
          kv[sr][scc + j * 4 + 3] = bf2f(u.w);
        }
      } else {
#pragma unroll
        for (int j = 0; j < 16; ++j) kv[sr][scc + j] = 0.f;
      }
    }
    __syncthreads();
#pragma unroll
    for (int jj = 0; jj < 4; ++jj) {
      int kj = l4 * 4 + jj;
      int tg = kt * 64 + kj;
      float acc = 0.f;
#pragma unroll
      for (int d = 0; d < 64; ++d) acc += qs[qi][d] * kv[kj][d];
      sc[qi][tg] = (tg < SS) ? acc : -1e30f;
    }
  }
  __syncthreads();
  // softmax over 384 (padding at -1e30 -> exp 0)
  float m = -1e30f;
  for (int tg = l4; tg < 384; tg += 16) m = fmaxf(m, sc[qi][tg]);
#pragma unroll
  for (int off = 8; off; off >>= 1) m = fmaxf(m, __shfl_xor(m, off, 16));
  float sum = 0.f;
  for (int tg = l4; tg < 384; tg += 16) {
    float e = __expf(sc[qi][tg] - m);
    sc[qi][tg] = e; sum += e;
  }
#pragma unroll
  for (int off = 8; off; off >>= 1) sum += __shfl_xor(sum, off, 16);
  float inv = 1.f / sum;
  // pass 2: PV
  float a0 = 0.f, a1 = 0.f, a2 = 0.f, a3 = 0.f;
  const int d0 = l4 * 4;
  for (int vt = 0; vt < 6; ++vt) {
    __syncthreads();
    {
      int sV = vt * 64 + sr;
      if (sV < SS) {
        const unsigned short* vp = KVb + ((size_t)(sV * BB + b)) * 1024 + 512 + h * 64 + scc;
#pragma unroll
        for (int j = 0; j < 4; ++j) {
          ushort4 u = *(const ushort4*)(vp + j * 4);
          kv[sr][scc + j * 4 + 0] = bf2f(u.x);
          kv[sr][scc + j * 4 + 1] = bf2f(u.y);
          kv[sr][scc + j * 4 + 2] = bf2f(u.z);
          kv[sr][scc + j * 4 + 3] = bf2f(u.w);
        }
      } else {
#pragma unroll
        for (int j = 0; j < 16; ++j) kv[sr][scc + j] = 0.f;
      }
    }
    __syncthreads();
#pragma unroll
    for (int tt = 0; tt < 64; ++tt) {
      float p = sc[qi][vt * 64 + tt];
      a0 += p * kv[tt][d0 + 0];
      a1 += p * kv[tt][d0 + 1];
      a2 += p * kv[tt][d0 + 2];
      a3 += p * kv[tt][d0 + 3];
    }
  }
  int s = s0 + qi;
  if (s < SS) {
    ushort4 st;
    st.x = f2bf(a0 * inv); st.y = f2bf(a1 * inv);
    st.z = f2bf(a2 * inv); st.w = f2bf(a3 * inv);
    *(ushort4*)(Ob + ((size_t)(s * BB + b)) * 512 + h * 64 + d0) = st;
  }
}

// ---------------- small VALU GEMM (M=64 only: stylization emb linears) --
template<int EPI>
__global__ __launch_bounds__(256) void gemm_tn(
    const float* __restrict__ A, const float* __restrict__ W,
    const float* __restrict__ bias, float* __restrict__ C,
    int M, int N, int K, int ldc) {
  __shared__ float As[16][64];
  __shared__ float Ws[16][64];
  const int tid = threadIdx.x;
  const int bm = blockIdx.y << 6;
  const int bn = blockIdx.x << 6;
  const int lr = tid >> 2;
  const int lk = (tid & 3) << 2;
  const float* Ap = A + (size_t)(bm + lr) * K + lk;
  const float* Wp = W + (size_t)(bn + lr) * K + lk;
  const int tx = tid & 15, ty = tid >> 4;
  float c[4][4] = {};
  for (int k0 = 0; k0 < K; k0 += 16) {
    float4 av = *(const float4*)(Ap + k0);
    float4 wv = *(const float4*)(Wp + k0);
    __syncthreads();
    As[lk + 0][lr] = av.x; As[lk + 1][lr] = av.y;
    As[lk + 2][lr] = av.z; As[lk + 3][lr] = av.w;
    Ws[lk + 0][lr] = wv.x; Ws[lk + 1][lr] = wv.y;
    Ws[lk + 2][lr] = wv.z; Ws[lk + 3][lr] = wv.w;
    __syncthreads();
#pragma unroll
    for (int k = 0; k < 16; ++k) {
      const float4 a = *(const float4*)&As[k][ty << 2];
      const float4 w = *(const float4*)&Ws[k][tx << 2];
      c[0][0] += a.x * w.x; c[0][1] += a.x * w.y; c[0][2] += a.x * w.z; c[0][3] += a.x * w.w;
      c[1][0] += a.y * w.x; c[1][1] += a.y * w.y; c[1][2] += a.y * w.z; c[1][3] += a.y * w.w;
      c[2][0] += a.z * w.x; c[2][1] += a.z * w.y; c[2][2] += a.z * w.z; c[2][3] += a.z * w.w;
      c[3][0] += a.w * w.x; c[3][1] += a.w * w.y; c[3][2] += a.w * w.z; c[3][3] += a.w * w.w;
    }
  }
#pragma unroll
  for (int i = 0; i < 4; ++i) {
    int row = bm + (ty << 2) + i;
    float* Cp = C + (size_t)row * ldc + bn + (tx << 2);
#pragma unroll
    for (int j = 0; j < 4; ++j) {
      float v = c[i][j] + bias[bn + (tx << 2) + j];
      if (EPI == 1) v = fmaxf(v, 0.f);
      if (EPI == 3) Cp[j] += v; else Cp[j] = v;
    }
  }
}

// ---------------- LayerNorm row kernel (D=512, 1 wave/row) -------------
__global__ __launch_bounds__(64) void ln_kernel(
    const float* __restrict__ in, const float* __restrict__ res,
    float* __restrict__ out, const float* __restrict__ g,
    const float* __restrict__ beta) {
  const int row = blockIdx.x;
  const int lane = threadIdx.x;
  const float* ip = in + (size_t)row * DD;
  float v[8];
  float s = 0.f, ss = 0.f;
#pragma unroll
  for (int u = 0; u < 2; ++u) {
    int d = u * 256 + lane * 4;
    float4 a = *(const float4*)(ip + d);
    if (res) {
      float4 r = *(const float4*)(res + (size_t)row * DD + d);
      a.x += r.x; a.y += r.y; a.z += r.z; a.w += r.w;
    }
    v[u * 4 + 0] = a.x; v[u * 4 + 1] = a.y; v[u * 4 + 2] = a.z; v[u * 4 + 3] = a.w;
    s += a.x + a.y + a.z + a.w;
    ss += a.x * a.x + a.y * a.y + a.z * a.z + a.w * a.w;
  }
#pragma unroll
  for (int off = 32; off; off >>= 1) { s += __shfl_xor(s, off); ss += __shfl_xor(ss, off); }
  float mean = s * (1.f / 512.f);
  float var = ss * (1.f / 512.f) - mean * mean;
  float rstd = rsqrtf(var + 1e-5f);
  float* op = out + (size_t)row * DD;
#pragma unroll
  for (int u = 0; u < 2; ++u) {
    int d = u * 256 + lane * 4;
    float4 o4;
    o4.x = (v[u * 4 + 0] - mean) * rstd * g[d + 0] + beta[d + 0];
    o4.y = (v[u * 4 + 1] - mean) * rstd * g[d + 1] + beta[d + 1];
    o4.z = (v[u * 4 + 2] - mean) * rstd * g[d + 2] + beta[d + 2];
    o4.w = (v[u * 4 + 3] - mean) * rstd * g[d + 3] + beta[d + 3];
    *(float4*)(op + d) = o4;
  }
}

// ---------------- stylization inner: silu(LN(y)*(1+scale)+shift) -------
__global__ __launch_bounds__(64) void styl_kernel(
    const float* __restrict__ y, const float* __restrict__ eo,
    const float* __restrict__ g, const float* __restrict__ beta,
    float* __restrict__ out) {
  const int row = blockIdx.x;         // b*TT + t
  const int b = row >> 8;
  const int lane = threadIdx.x;
  const float* ip = y + (size_t)row * DD;
  const float* sc = eo + (size_t)b * 1024;
  float v[8];
  float s = 0.f, ss = 0.f;
#pragma unroll
  for (int u = 0; u < 2; ++u) {
    int d = u * 256 + lane * 4;
    float4 a = *(const float4*)(ip + d);
    v[u * 4 + 0] = a.x; v[u * 4 + 1] = a.y; v[u * 4 + 2] = a.z; v[u * 4 + 3] = a.w;
    s += a.x + a.y + a.z + a.w;
    ss += a.x * a.x + a.y * a.y + a.z * a.z + a.w * a.w;
  }
#pragma unroll
  for (int off = 32; off; off >>= 1) { s += __shfl_xor(s, off); ss += __shfl_xor(ss, off); }
  float mean = s * (1.f / 512.f);
  float var = ss * (1.f / 512.f) - mean * mean;
  float rstd = rsqrtf(var + 1e-5f);
  float* op = out + (size_t)row * DD;
#pragma unroll
  for (int u = 0; u < 2; ++u) {
    int d0 = u * 256 + lane * 4;
#pragma unroll
    for (int j = 0; j < 4; ++j) {
      int d = d0 + j;
      float ln = (v[u * 4 + j] - mean) * rstd * g[d] + beta[d];
      float h = ln * (1.f + sc[d]) + sc[512 + d];
      op[d] = h / (1.f + __expf(-h));
    }
  }
}

// ---------------- per-64-group softmax (qc, last axis) -----------------
__global__ __launch_bounds__(512) void softmax64_kernel(float* __restrict__ a) {
  int row = blockIdx.x;
  int lane = threadIdx.x & 63;
  int h = threadIdx.x >> 6;
  float* p = a + (size_t)row * DD + h * 64;
  float v = p[lane];
  float m = v;
#pragma unroll
  for (int off = 32; off; off >>= 1) m = fmaxf(m, __shfl_xor(m, off));
  float e = __expf(v - m);
  float sum = e;
#pragma unroll
  for (int off = 32; off; off >>= 1) sum += __shfl_xor(sum, off);
  p[lane] = e / sum;
}

// ---------------- softmax over n (kc, axis=1, 77 tokens) ---------------
__global__ __launch_bounds__(256) void softmax_n_kernel(float* __restrict__ a) {
  int b = blockIdx.x;
  int c = blockIdx.y * 256 + threadIdx.x;     // 0..511
  float* p = a + ((size_t)b * NN) * DD + c;
  float m = -1e30f;
  for (int n = 0; n < NN; ++n) m = fmaxf(m, p[(size_t)n * DD]);
  float sum = 0.f;
  for (int n = 0; n < NN; ++n) sum += __expf(p[(size_t)n * DD] - m);
  float inv = 1.f / sum;
  for (int n = 0; n < NN; ++n) p[(size_t)n * DD] = __expf(p[(size_t)n * DD] - m) * inv;
}

// ---------------- ctx[b,h,d,l] = sum_n kc[b,n,h,d]*vc[b,n,h,l] ---------
__global__ __launch_bounds__(256) void ctx_kernel(
    const float* __restrict__ kc, const float* __restrict__ vc,
    float* __restrict__ ctx) {
  __shared__ float ks[NN][64];
  __shared__ float vs[NN][64];
  int bh = blockIdx.x; int b = bh >> 3, h = bh & 7;
  for (int l = threadIdx.x; l < NN * 64; l += 256) {
    int n = l >> 6, d = l & 63;
    size_t idx = ((size_t)(b * NN + n)) * DD + h * 64 + d;
    ks[n][d] = kc[idx];
    vs[n][d] = vc[idx];
  }
  __syncthreads();
  int d = threadIdx.x >> 2;
  int l0 = (threadIdx.x & 3) << 4;
  float acc[16] = {};
  for (int n = 0; n < NN; ++n) {
    float kd = ks[n][d];
#pragma unroll
    for (int j = 0; j < 16; ++j) acc[j] += kd * vs[n][l0 + j];
  }
  float* cp = ctx + ((size_t)bh * 64 + d) * 64 + l0;
#pragma unroll
  for (int j = 0; j < 16; ++j) cp[j] = acc[j];
}

// ---------------- y[b,t,h,l] = sum_d qc[b,t,h,d]*ctx[b,h,d,l] ----------
__global__ __launch_bounds__(256) void lin_y_kernel(
    const float* __restrict__ qc, const float* __restrict__ ctx,
    float* __restrict__ y) {
  __shared__ float cs[64][64];
  int bh = blockIdx.x; int b = bh >> 3, h = bh & 7;
  for (int l = threadIdx.x; l < 4096; l += 256)
    cs[l >> 6][l & 63] = ctx[(size_t)bh * 4096 + l];
  __syncthreads();
  int tg = threadIdx.x >> 6, l = threadIdx.x & 63;
  for (int t = tg * 64; t < tg * 64 + 64; ++t) {
    const float* qp = qc + ((size_t)(b * TT + t)) * DD + h * 64;
    float acc = 0.f;
#pragma unroll
    for (int d2 = 0; d2 < 64; ++d2) acc += qp[d2] * cs[d2][l];
    y[((size_t)(b * TT + t)) * DD + h * 64 + l] = acc;
  }
}

// ---------------- silu elementwise ------------------------------------
__global__ __launch_bounds__(256) void silu_kernel(
    const float* __restrict__ in, float* __restrict__ out, int n) {
  int i = blockIdx.x * 256 + threadIdx.x;
  if (i < n) { float v = in[i]; out[i] = v / (1.f + __expf(-v)); }
}

// ---------------- transposes ------------------------------------------
__global__ __launch_bounds__(256) void t2b_kernel(
    const float* __restrict__ srcm, float* __restrict__ dst, int Rr) {
  int idx = blockIdx.x * 256 + threadIdx.x;
  if (idx >= Rr * BB * 128) return;
  int c4 = idx & 127;
  int row = idx >> 7;                  // b*Rr + r
  int b = row / Rr, r = row % Rr;
  ((float4*)(dst + (size_t)row * DD))[c4] =
      ((const float4*)(srcm + ((size_t)(r * BB + b)) * DD))[c4];
}
__global__ __launch_bounds__(256) void b2t_kernel(
    const float* __restrict__ xb, float* __restrict__ out) {
  int idx = blockIdx.x * 256 + threadIdx.x;
  if (idx >= TT * BB * 128) return;
  int c4 = idx & 127;
  int row = idx >> 7;                  // t*BB + b
  int t = row >> 6, b = row & 63;
  ((float4*)(out + (size_t)row * DD))[c4] =
      ((const float4*)(xb + ((size_t)(b * TT + t)) * DD))[c4];
}

extern "C" void kernel_launch(void* const* d_in, const int* in_sizes, int n_in,
                              void* d_out, int out_size, void* d_ws, size_t ws_size,
                              hipStream_t stream) {
  const float* x       = (const float*)d_in[0];
  const float* xf      = (const float*)d_in[1];
  const float* emb     = (const float*)d_in[2];
  const float* sa_in_w = (const float*)d_in[3];
  const float* sa_in_b = (const float*)d_in[4];
  const float* sa_out_w= (const float*)d_in[5];
  const float* sa_out_b= (const float*)d_in[6];
  const float* sa_l1_w = (const float*)d_in[7];
  const float* sa_l1_b = (const float*)d_in[8];
  const float* sa_l2_w = (const float*)d_in[9];
  const float* sa_l2_b = (const float*)d_in[10];
  const float* sa_n1_g = (const float*)d_in[11];
  const float* sa_n1_b = (const float*)d_in[12];
  const float* sa_n2_g = (const float*)d_in[13];
  const float* sa_n2_b = (const float*)d_in[14];
  const float* ca_norm_g = (const float*)d_in[15];
  const float* ca_norm_b = (const float*)d_in[16];
  const float* ca_tnorm_g= (const float*)d_in[17];
  const float* ca_tnorm_b= (const float*)d_in[18];
  const float* ca_q_w  = (const float*)d_in[19];
  const float* ca_q_b  = (const float*)d_in[20];
  const float* ca_k_w  = (const float*)d_in[21];
  const float* ca_k_b  = (const float*)d_in[22];
  const float* ca_v_w  = (const float*)d_in[23];
  const float* ca_v_b  = (const float*)d_in[24];
  const float* ca_se_w = (const float*)d_in[25];
  const float* ca_se_b = (const float*)d_in[26];
  const float* ca_sn_g = (const float*)d_in[27];
  const float* ca_sn_b = (const float*)d_in[28];
  const float* ca_so_w = (const float*)d_in[29];
  const float* ca_so_b = (const float*)d_in[30];
  const float* ff_l1_w = (const float*)d_in[31];
  const float* ff_l1_b = (const float*)d_in[32];
  const float* ff_l2_w = (const float*)d_in[33];
  const float* ff_l2_b = (const float*)d_in[34];
  const float* ff_se_w = (const float*)d_in[35];
  const float* ff_se_b = (const float*)d_in[36];
  const float* ff_sn_g = (const float*)d_in[37];
  const float* ff_sn_b = (const float*)d_in[38];
  const float* ff_so_w = (const float*)d_in[39];
  const float* ff_so_b = (const float*)d_in[40];

  float* R1 = (float*)d_ws;
  float* R2 = R1 + REG;
  float* R3 = R2 + REG;

  // Phase A aliases
  float* src = R1;
  unsigned short* Qbf  = (unsigned short*)R3;                 // [M1,512] bf16
  unsigned short* Obf  = (unsigned short*)(R3 + 5472256);     // [M1,512] bf16
  unsigned short* KVbf = (unsigned short*)R2;                 // [M1,1024] bf16
  float* proj  = R2;                                          // after KV dead
  unsigned short* h1bf = (unsigned short*)R2;                 // [M1,1024] bf16
  float* proj2 = R3;                                          // after Q/O dead
  // Phase B aliases
  float* xb  = R3;                      // [M2,512]
  float* tnb = R3 + 8388608;            // [BB*NN,512]
  float* xn  = R1;                      // [M2,512]
  float* kc  = R1;                      // [BB*NN,512]
  float* vc  = R1 + 2523136;
  float* ctxb= R1 + 5046272;            // [512,64,64]
  float* yb  = R2;                      // [M2,512]
  float* se  = R2 + 8388608;            // [64,512]
  float* eo  = se + 32768;              // [64,1024]
  float* eo2 = eo + 65536;              // [64,1024]
  float* qc  = (float*)d_out;           // [M2,512] scratch
  float* hst = (float*)d_out;
  // Phase C aliases
  unsigned short* g1bf = (unsigned short*)R2;   // [8192,2048] bf16 per half
  float* y2 = R1;                       // [M2,512]

  // ---------- Phase A: self-attention transformer block ----------
  concat_src_kernel<<<10688, 256, 0, stream>>>(x, xf, emb, src);
  gemm_mfma<0, false, true><<<dim3(4, 167), 256, 0, stream>>>(
      src, sa_in_w, sa_in_b, Qbf, M1, 512, 512);
  gemm_mfma<0, false, true><<<dim3(8, 167), 256, 0, stream>>>(
      src, sa_in_w + (size_t)512 * 512, sa_in_b + 512, KVbf, M1, 512, 1024);
  attn2_kernel<<<dim3(21, BB * HH), 256, 0, stream>>>(Qbf, KVbf, Obf);
  gemm_mfma<0, true, false><<<dim3(4, 167), 256, 0, stream>>>(
      Obf, sa_out_w, sa_out_b, proj, M1, 512, 512);
  ln_kernel<<<M1, 64, 0, stream>>>(src, proj, src, sa_n1_g, sa_n1_b);
  gemm_mfma<1, false, true><<<dim3(8, 167), 256, 0, stream>>>(
      src, sa_l1_w, sa_l1_b, h1bf, M1, 512, 1024);
  gemm_mfma<0, true, false><<<dim3(4, 167), 256, 0, stream>>>(
      h1bf, sa_l2_w, sa_l2_b, proj2, M1, 1024, 512);
  ln_kernel<<<M1, 64, 0, stream>>>(src, proj2, src, sa_n2_g, sa_n2_b);

  // ---------- Phase B: linear cross-attention + stylization ----------
  t2b_kernel<<<8192, 256, 0, stream>>>(src, xb, TT);
  ln_kernel<<<M2, 64, 0, stream>>>(xb, nullptr, xn, ca_norm_g, ca_norm_b);
  gemm_mfma<0, false, false><<<dim3(4, 128), 256, 0, stream>>>(
      xn, ca_q_w, ca_q_b, qc, M2, 512, 512);
  softmax64_kernel<<<M2, 512, 0, stream>>>(qc);
  t2b_kernel<<<2464, 256, 0, stream>>>(xf, tnb, NN);
  ln_kernel<<<BB * NN, 64, 0, stream>>>(tnb, nullptr, tnb, ca_tnorm_g, ca_tnorm_b);
  gemm_mfma<0, false, false><<<dim3(4, 39), 256, 0, stream>>>(
      tnb, ca_k_w, ca_k_b, kc, BB * NN, 512, 512);
  softmax_n_kernel<<<dim3(64, 2), 256, 0, stream>>>(kc);
  gemm_mfma<0, false, false><<<dim3(4, 39), 256, 0, stream>>>(
      tnb, ca_v_w, ca_v_b, vc, BB * NN, 512, 512);
  ctx_kernel<<<BB * HH, 256, 0, stream>>>(kc, vc, ctxb);
  silu_kernel<<<128, 256, 0, stream>>>(emb, se, BB * DD);
  gemm_tn<0><<<dim3(16, 1), 256, 0, stream>>>(se, ca_se_w, ca_se_b, eo, BB, 1024, DD, 1024);
  gemm_tn<0><<<dim3(16, 1), 256, 0, stream>>>(se, ff_se_w, ff_se_b, eo2, BB, 1024, DD, 1024);
  lin_y_kernel<<<BB * HH, 256, 0, stream>>>(qc, ctxb, yb);
  styl_kernel<<<M2, 64, 0, stream>>>(yb, eo, ca_sn_g, ca_sn_b, hst);
  gemm_mfma<3, false, false><<<dim3(4, 128), 256, 0, stream>>>(
      hst, ca_so_w, ca_so_b, xb, M2, 512, 512);

  // ---------- Phase C: FFN + stylization (two M-halves) ----------
  for (int hlf = 0; hlf < 2; ++hlf) {
    size_t m0 = (size_t)hlf * 8192;
    gemm_mfma<2, false, true><<<dim3(16, 64), 256, 0, stream>>>(
        xb + m0 * DD, ff_l1_w, ff_l1_b, g1bf, 8192, 512, 2048);
    gemm_mfma<0, true, false><<<dim3(4, 64), 256, 0, stream>>>(
        g1bf, ff_l2_w, ff_l2_b, y2 + m0 * DD, 8192, 2048, 512);
  }
  styl_kernel<<<M2, 64, 0, stream>>>(y2, eo2, ff_sn_g, ff_sn_b, (float*)d_out);
  gemm_mfma<3, false, false><<<dim3(4, 128), 256, 0, stream>>>(
      (float*)d_out, ff_so_w, ff_so_b, xb, M2, 512, 512);

  // ---------- output transpose ----------
  b2t_kernel<<<8192, 256, 0, stream>>>(xb, (float*)d_out);
}

// Round 6
// 1090.302 us; speedup vs baseline: 6.0525x; 2.0998x over previous
//
#include <hip/hip_runtime.h>
#include <hip/hip_bf16.h>
#include <cstddef>

// Problem dims
#define TT 256
#define BB 64
#define NN 77
#define DD 512
#define SS 334            // T + N + 1
#define HH 8
#define M1 (SS*BB)        // 21376
#define M2 (BB*TT)        // 16384
#define FFSA 1024
#define FF 2048

// Workspace: 3 regions of 10,944,512 floats each (125.25 MiB total, proven OK).
#define REG 10944512ULL

typedef __attribute__((ext_vector_type(4))) float f32x4;
typedef __attribute__((ext_vector_type(8))) short bf16x8;
typedef __attribute__((ext_vector_type(8))) unsigned short u16x8;

__device__ inline unsigned short f2bf(float f) {
  __hip_bfloat16 h = __float2bfloat16(f);
  return *reinterpret_cast<unsigned short*>(&h);
}
__device__ inline float bf2f(unsigned short u) {
  return __uint_as_float(((unsigned)u) << 16);
}

// ---------------- concat [x; xf; emb] -> src (f32) ----------------
__global__ __launch_bounds__(256) void concat_src_kernel(
    const float* __restrict__ x, const float* __restrict__ xf,
    const float* __restrict__ emb, float* __restrict__ src) {
  int idx = blockIdx.x * 256 + threadIdx.x;      // float4 index
  if (idx >= SS * BB * 128) return;
  int c4 = idx & 127;
  int row = idx >> 7;                            // s*BB + b
  int s = row >> 6, b = row & 63;
  const float* p;
  if (s < TT)            p = x   + ((size_t)(s * BB + b)) * DD;
  else if (s < TT + NN)  p = xf  + ((size_t)((s - TT) * BB + b)) * DD;
  else                   p = emb + (size_t)b * DD;
  ((float4*)(src + (size_t)row * DD))[c4] = ((const float4*)p)[c4];
}

// ---------------- MFMA GEMM: C = epi(A[M,K] @ W[N,K]^T + bias) --------
// 128x128 tile, 4 waves (each 64x64), 16x16x32 bf16 MFMA, BK=32.
template<int EPI, bool ABF, bool CBF>
__global__ __launch_bounds__(256) void gemm_mfma(
    const void* __restrict__ Ap_, const float* __restrict__ W,
    const float* __restrict__ bias, void* __restrict__ Cp_,
    int M, int K, int ldc) {
  __shared__ unsigned short As[4][128][8];   // [k-chunk][row][k-in-chunk]
  __shared__ unsigned short Bs[4][128][8];
  const int tid = threadIdx.x;
  const int bm = blockIdx.y * 128;
  const int bn = blockIdx.x * 128;
  const int lane = tid & 63;
  const int wave = tid >> 6;
  const int wr = wave >> 1, wc = wave & 1;      // 2x2 wave grid of 64x64
  const int q = lane >> 4, lr = lane & 15;

  f32x4 acc[4][4];
#pragma unroll
  for (int m = 0; m < 4; ++m)
#pragma unroll
    for (int n = 0; n < 4; ++n) acc[m][n] = (f32x4){0.f, 0.f, 0.f, 0.f};

  const int srow = tid >> 1;
  const int skc = (tid & 1) * 16;
  int arow = bm + srow; if (arow >= M) arow = M - 1;
  const int brow = bn + srow;

  for (int k0 = 0; k0 < K; k0 += 32) {
    u16x8 av0, av1, bv0, bv1;
    if (ABF) {
      const unsigned short* Ar = (const unsigned short*)Ap_ + (size_t)arow * K + k0 + skc;
      av0 = *(const u16x8*)Ar;
      av1 = *(const u16x8*)(Ar + 8);
    } else {
      const float* Ar = (const float*)Ap_ + (size_t)arow * K + k0 + skc;
#pragma unroll
      for (int j = 0; j < 8; ++j) av0[j] = f2bf(Ar[j]);
#pragma unroll
      for (int j = 0; j < 8; ++j) av1[j] = f2bf(Ar[8 + j]);
    }
    {
      const float* Wr = W + (size_t)brow * K + k0 + skc;
#pragma unroll
      for (int j = 0; j < 8; ++j) bv0[j] = f2bf(Wr[j]);
#pragma unroll
      for (int j = 0; j < 8; ++j) bv1[j] = f2bf(Wr[8 + j]);
    }
    __syncthreads();
    const int c0 = skc >> 3;
    *(u16x8*)&As[c0][srow][0] = av0;
    *(u16x8*)&As[c0 + 1][srow][0] = av1;
    *(u16x8*)&Bs[c0][srow][0] = bv0;
    *(u16x8*)&Bs[c0 + 1][srow][0] = bv1;
    __syncthreads();
    bf16x8 af[4], bf[4];
#pragma unroll
    for (int m = 0; m < 4; ++m) af[m] = *(const bf16x8*)&As[q][wr * 64 + m * 16 + lr][0];
#pragma unroll
    for (int n = 0; n < 4; ++n) bf[n] = *(const bf16x8*)&Bs[q][wc * 64 + n * 16 + lr][0];
#pragma unroll
    for (int m = 0; m < 4; ++m)
#pragma unroll
      for (int n = 0; n < 4; ++n)
        acc[m][n] = __builtin_amdgcn_mfma_f32_16x16x32_bf16(af[m], bf[n], acc[m][n], 0, 0, 0);
  }

#pragma unroll
  for (int m = 0; m < 4; ++m) {
#pragma unroll
    for (int n = 0; n < 4; ++n) {
      const int col = bn + wc * 64 + n * 16 + lr;
      const float bb = bias[col];
#pragma unroll
      for (int i = 0; i < 4; ++i) {
        const int row = bm + wr * 64 + m * 16 + q * 4 + i;
        if (row < M) {
          float v = acc[m][n][i] + bb;
          if (EPI == 1) v = fmaxf(v, 0.f);
          if (EPI == 2) v = 0.5f * v * (1.f + erff(v * 0.70710678118f));
          if (CBF) {
            ((unsigned short*)Cp_)[(size_t)row * ldc + col] = f2bf(v);
          } else {
            float* C = (float*)Cp_ + (size_t)row * ldc + col;
            if (EPI == 3) *C += v; else *C = v;
          }
        }
      }
    }
  }
}

// ---------------- MFMA flash attention --------------------------------
// Q_bf [M1,512] (row s*BB+b, col h*64+d); KV_bf [M1,1024] (K at h*64, V at 512+h*64)
// grid (6, BB*HH); 256 threads (4 waves); 64 queries per block.
// Fragment layouts as verified by gemm_mfma: A row=lane&15, k=(lane>>4)*8+j;
// B col=lane&15, k=(lane>>4)*8+j; C col=lane&15, row=(lane>>4)*4+i.
__global__ __launch_bounds__(256) void attn_mfma_kernel(
    const unsigned short* __restrict__ Qb, const unsigned short* __restrict__ KVb,
    unsigned short* __restrict__ Ob) {
  __shared__ unsigned short Qs[64][72];
  __shared__ unsigned short Ks[64][72];
  __shared__ unsigned short Vt[64][72];      // transposed: Vt[d][t]
  __shared__ unsigned short Ps[4][16][72];   // per-wave P tile
  const int bh = blockIdx.y, b = bh >> 3, h = bh & 7;
  const int s0 = blockIdx.x << 6;
  const int tid = threadIdx.x;
  const int wave = tid >> 6, lane = tid & 63;
  const int q = lane >> 4, lr = lane & 15;
  const int sr = tid >> 2;            // staging row 0..63
  const int c0 = (tid & 3) << 4;      // staging col group of 16

  // stage Q tile (rows s0..s0+63)
  {
    int s = s0 + sr;
    u16x8 v0 = {0, 0, 0, 0, 0, 0, 0, 0}, v1 = v0;
    if (s < SS) {
      const unsigned short* qp = Qb + ((size_t)(s * BB + b)) * 512 + h * 64 + c0;
      v0 = *(const u16x8*)qp; v1 = *(const u16x8*)(qp + 8);
    }
    *(u16x8*)&Qs[sr][c0] = v0;
    *(u16x8*)&Qs[sr][c0 + 8] = v1;
  }

  f32x4 oacc[4];
#pragma unroll
  for (int dt = 0; dt < 4; ++dt) oacc[dt] = (f32x4){0.f, 0.f, 0.f, 0.f};
  float m_r[4] = {-1e30f, -1e30f, -1e30f, -1e30f};
  float l_r[4] = {0.f, 0.f, 0.f, 0.f};

  for (int kt = 0; kt < 6; ++kt) {
    __syncthreads();   // prior iteration done with Ks/Vt (and Q staged, iter 0)
    {
      int t = kt * 64 + sr;
      u16x8 k0 = {0, 0, 0, 0, 0, 0, 0, 0}, k1 = k0, w0 = k0, w1 = k0;
      if (t < SS) {
        const unsigned short* kp = KVb + ((size_t)(t * BB + b)) * 1024 + h * 64 + c0;
        k0 = *(const u16x8*)kp; k1 = *(const u16x8*)(kp + 8);
        w0 = *(const u16x8*)(kp + 512); w1 = *(const u16x8*)(kp + 520);
      }
      *(u16x8*)&Ks[sr][c0] = k0;
      *(u16x8*)&Ks[sr][c0 + 8] = k1;
#pragma unroll
      for (int j = 0; j < 8; ++j) Vt[c0 + j][sr] = w0[j];
#pragma unroll
      for (int j = 0; j < 8; ++j) Vt[c0 + 8 + j][sr] = w1[j];
    }
    __syncthreads();
    // S = Q K^T  (16 rows per wave x 64 keys)
    f32x4 sacc[4];
#pragma unroll
    for (int ct = 0; ct < 4; ++ct) sacc[ct] = (f32x4){0.f, 0.f, 0.f, 0.f};
#pragma unroll
    for (int kc = 0; kc < 2; ++kc) {
      bf16x8 aq = *(const bf16x8*)&Qs[wave * 16 + lr][kc * 32 + q * 8];
#pragma unroll
      for (int ct = 0; ct < 4; ++ct) {
        bf16x8 bk = *(const bf16x8*)&Ks[ct * 16 + lr][kc * 32 + q * 8];
        sacc[ct] = __builtin_amdgcn_mfma_f32_16x16x32_bf16(aq, bk, sacc[ct], 0, 0, 0);
      }
    }
    // online softmax update (per row i; row = q*4+i, col = ct*16+lr)
    float pexp[4][4];
#pragma unroll
    for (int i = 0; i < 4; ++i) {
      float mt = -1e30f;
#pragma unroll
      for (int ct = 0; ct < 4; ++ct) {
        float sv = sacc[ct][i] * 0.125f;
        if (kt * 64 + ct * 16 + lr >= SS) sv = -1e30f;
        sacc[ct][i] = sv;
        mt = fmaxf(mt, sv);
      }
#pragma unroll
      for (int off = 8; off; off >>= 1) mt = fmaxf(mt, __shfl_xor(mt, off));
      float mn = fmaxf(m_r[i], mt);
      float rescale = __expf(m_r[i] - mn);
      m_r[i] = mn;
      float se = 0.f;
#pragma unroll
      for (int ct = 0; ct < 4; ++ct) {
        float e = __expf(sacc[ct][i] - mn);
        pexp[ct][i] = e;
        se += e;
      }
#pragma unroll
      for (int off = 8; off; off >>= 1) se += __shfl_xor(se, off);
      l_r[i] = l_r[i] * rescale + se;
#pragma unroll
      for (int dt = 0; dt < 4; ++dt) oacc[dt][i] *= rescale;
    }
    // P tile -> per-wave LDS (C-layout write)
#pragma unroll
    for (int ct = 0; ct < 4; ++ct)
#pragma unroll
      for (int i = 0; i < 4; ++i)
        Ps[wave][q * 4 + i][ct * 16 + lr] = f2bf(pexp[ct][i]);
    // O += P V   (A-layout read of P; Vt gives contiguous B-frags)
#pragma unroll
    for (int kc = 0; kc < 2; ++kc) {
      bf16x8 ap = *(const bf16x8*)&Ps[wave][lr][kc * 32 + q * 8];
#pragma unroll
      for (int dt = 0; dt < 4; ++dt) {
        bf16x8 bv = *(const bf16x8*)&Vt[dt * 16 + lr][kc * 32 + q * 8];
        oacc[dt] = __builtin_amdgcn_mfma_f32_16x16x32_bf16(ap, bv, oacc[dt], 0, 0, 0);
      }
    }
  }
  // epilogue
#pragma unroll
  for (int i = 0; i < 4; ++i) {
    int s = s0 + wave * 16 + q * 4 + i;
    if (s < SS) {
      float inv = 1.f / l_r[i];
      unsigned short* op = Ob + ((size_t)(s * BB + b)) * 512 + h * 64;
#pragma unroll
      for (int dt = 0; dt < 4; ++dt)
        op[dt * 16 + lr] = f2bf(oacc[dt][i] * inv);
    }
  }
}

// ---------------- small VALU GEMM (M=64 only: stylization emb linears) --
template<int EPI>
__global__ __launch_bounds__(256) void gemm_tn(
    const float* __restrict__ A, const float* __restrict__ W,
    const float* __restrict__ bias, float* __restrict__ C,
    int M, int N, int K, int ldc) {
  __shared__ float As[16][64];
  __shared__ float Ws[16][64];
  const int tid = threadIdx.x;
  const int bm = blockIdx.y << 6;
  const int bn = blockIdx.x << 6;
  const int lr = tid >> 2;
  const int lk = (tid & 3) << 2;
  const float* Ap = A + (size_t)(bm + lr) * K + lk;
  const float* Wp = W + (size_t)(bn + lr) * K + lk;
  const int tx = tid & 15, ty = tid >> 4;
  float c[4][4] = {};
  for (int k0 = 0; k0 < K; k0 += 16) {
    float4 av = *(const float4*)(Ap + k0);
    float4 wv = *(const float4*)(Wp + k0);
    __syncthreads();
    As[lk + 0][lr] = av.x; As[lk + 1][lr] = av.y;
    As[lk + 2][lr] = av.z; As[lk + 3][lr] = av.w;
    Ws[lk + 0][lr] = wv.x; Ws[lk + 1][lr] = wv.y;
    Ws[lk + 2][lr] = wv.z; Ws[lk + 3][lr] = wv.w;
    __syncthreads();
#pragma unroll
    for (int k = 0; k < 16; ++k) {
      const float4 a = *(const float4*)&As[k][ty << 2];
      const float4 w = *(const float4*)&Ws[k][tx << 2];
      c[0][0] += a.x * w.x; c[0][1] += a.x * w.y; c[0][2] += a.x * w.z; c[0][3] += a.x * w.w;
      c[1][0] += a.y * w.x; c[1][1] += a.y * w.y; c[1][2] += a.y * w.z; c[1][3] += a.y * w.w;
      c[2][0] += a.z * w.x; c[2][1] += a.z * w.y; c[2][2] += a.z * w.z; c[2][3] += a.z * w.w;
      c[3][0] += a.w * w.x; c[3][1] += a.w * w.y; c[3][2] += a.w * w.z; c[3][3] += a.w * w.w;
    }
  }
#pragma unroll
  for (int i = 0; i < 4; ++i) {
    int row = bm + (ty << 2) + i;
    float* Cp = C + (size_t)row * ldc + bn + (tx << 2);
#pragma unroll
    for (int j = 0; j < 4; ++j) {
      float v = c[i][j] + bias[bn + (tx << 2) + j];
      if (EPI == 1) v = fmaxf(v, 0.f);
      if (EPI == 3) Cp[j] += v; else Cp[j] = v;
    }
  }
}

// ---------------- LayerNorm row kernel (D=512, 1 wave/row) -------------
__global__ __launch_bounds__(64) void ln_kernel(
    const float* __restrict__ in, const float* __restrict__ res,
    float* __restrict__ out, const float* __restrict__ g,
    const float* __restrict__ beta) {
  const int row = blockIdx.x;
  const int lane = threadIdx.x;
  const float* ip = in + (size_t)row * DD;
  float v[8];
  float s = 0.f, ss = 0.f;
#pragma unroll
  for (int u = 0; u < 2; ++u) {
    int d = u * 256 + lane * 4;
    float4 a = *(const float4*)(ip + d);
    if (res) {
      float4 r = *(const float4*)(res + (size_t)row * DD + d);
      a.x += r.x; a.y += r.y; a.z += r.z; a.w += r.w;
    }
    v[u * 4 + 0] = a.x; v[u * 4 + 1] = a.y; v[u * 4 + 2] = a.z; v[u * 4 + 3] = a.w;
    s += a.x + a.y + a.z + a.w;
    ss += a.x * a.x + a.y * a.y + a.z * a.z + a.w * a.w;
  }
#pragma unroll
  for (int off = 32; off; off >>= 1) { s += __shfl_xor(s, off); ss += __shfl_xor(ss, off); }
  float mean = s * (1.f / 512.f);
  float var = ss * (1.f / 512.f) - mean * mean;
  float rstd = rsqrtf(var + 1e-5f);
  float* op = out + (size_t)row * DD;
#pragma unroll
  for (int u = 0; u < 2; ++u) {
    int d = u * 256 + lane * 4;
    float4 o4;
    o4.x = (v[u * 4 + 0] - mean) * rstd * g[d + 0] + beta[d + 0];
    o4.y = (v[u * 4 + 1] - mean) * rstd * g[d + 1] + beta[d + 1];
    o4.z = (v[u * 4 + 2] - mean) * rstd * g[d + 2] + beta[d + 2];
    o4.w = (v[u * 4 + 3] - mean) * rstd * g[d + 3] + beta[d + 3];
    *(float4*)(op + d) = o4;
  }
}

// ---------------- stylization inner: silu(LN(y)*(1+scale)+shift) -------
__global__ __launch_bounds__(64) void styl_kernel(
    const float* __restrict__ y, const float* __restrict__ eo,
    const float* __restrict__ g, const float* __restrict__ beta,
    float* __restrict__ out) {
  const int row = blockIdx.x;         // b*TT + t
  const int b = row >> 8;
  const int lane = threadIdx.x;
  const float* ip = y + (size_t)row * DD;
  const float* sc = eo + (size_t)b * 1024;
  float v[8];
  float s = 0.f, ss = 0.f;
#pragma unroll
  for (int u = 0; u < 2; ++u) {
    int d = u * 256 + lane * 4;
    float4 a = *(const float4*)(ip + d);
    v[u * 4 + 0] = a.x; v[u * 4 + 1] = a.y; v[u * 4 + 2] = a.z; v[u * 4 + 3] = a.w;
    s += a.x + a.y + a.z + a.w;
    ss += a.x * a.x + a.y * a.y + a.z * a.z + a.w * a.w;
  }
#pragma unroll
  for (int off = 32; off; off >>= 1) { s += __shfl_xor(s, off); ss += __shfl_xor(ss, off); }
  float mean = s * (1.f / 512.f);
  float var = ss * (1.f / 512.f) - mean * mean;
  float rstd = rsqrtf(var + 1e-5f);
  float* op = out + (size_t)row * DD;
#pragma unroll
  for (int u = 0; u < 2; ++u) {
    int d0 = u * 256 + lane * 4;
#pragma unroll
    for (int j = 0; j < 4; ++j) {
      int d = d0 + j;
      float ln = (v[u * 4 + j] - mean) * rstd * g[d] + beta[d];
      float h = ln * (1.f + sc[d]) + sc[512 + d];
      op[d] = h / (1.f + __expf(-h));
    }
  }
}

// ---------------- per-64-group softmax (qc, last axis) -----------------
__global__ __launch_bounds__(512) void softmax64_kernel(float* __restrict__ a) {
  int row = blockIdx.x;
  int lane = threadIdx.x & 63;
  int h = threadIdx.x >> 6;
  float* p = a + (size_t)row * DD + h * 64;
  float v = p[lane];
  float m = v;
#pragma unroll
  for (int off = 32; off; off >>= 1) m = fmaxf(m, __shfl_xor(m, off));
  float e = __expf(v - m);
  float sum = e;
#pragma unroll
  for (int off = 32; off; off >>= 1) sum += __shfl_xor(sum, off);
  p[lane] = e / sum;
}

// ---------------- softmax over n (kc, axis=1, 77 tokens) ---------------
__global__ __launch_bounds__(256) void softmax_n_kernel(float* __restrict__ a) {
  int b = blockIdx.x;
  int c = blockIdx.y * 256 + threadIdx.x;     // 0..511
  float* p = a + ((size_t)b * NN) * DD + c;
  float m = -1e30f;
  for (int n = 0; n < NN; ++n) m = fmaxf(m, p[(size_t)n * DD]);
  float sum = 0.f;
  for (int n = 0; n < NN; ++n) sum += __expf(p[(size_t)n * DD] - m);
  float inv = 1.f / sum;
  for (int n = 0; n < NN; ++n) p[(size_t)n * DD] = __expf(p[(size_t)n * DD] - m) * inv;
}

// ---------------- ctx[b,h,d,l] = sum_n kc[b,n,h,d]*vc[b,n,h,l] ---------
__global__ __launch_bounds__(256) void ctx_kernel(
    const float* __restrict__ kc, const float* __restrict__ vc,
    float* __restrict__ ctx) {
  __shared__ float ks[NN][64];
  __shared__ float vs[NN][64];
  int bh = blockIdx.x; int b = bh >> 3, h = bh & 7;
  for (int l = threadIdx.x; l < NN * 64; l += 256) {
    int n = l >> 6, d = l & 63;
    size_t idx = ((size_t)(b * NN + n)) * DD + h * 64 + d;
    ks[n][d] = kc[idx];
    vs[n][d] = vc[idx];
  }
  __syncthreads();
  int d = threadIdx.x >> 2;
  int l0 = (threadIdx.x & 3) << 4;
  float acc[16] = {};
  for (int n = 0; n < NN; ++n) {
    float kd = ks[n][d];
#pragma unroll
    for (int j = 0; j < 16; ++j) acc[j] += kd * vs[n][l0 + j];
  }
  float* cp = ctx + ((size_t)bh * 64 + d) * 64 + l0;
#pragma unroll
  for (int j = 0; j < 16; ++j) cp[j] = acc[j];
}

// ---------------- y[b,t,h,l] = sum_d qc[b,t,h,d]*ctx[b,h,d,l] ----------
__global__ __launch_bounds__(256) void lin_y_kernel(
    const float* __restrict__ qc, const float* __restrict__ ctx,
    float* __restrict__ y) {
  __shared__ float cs[64][64];
  int bh = blockIdx.x; int b = bh >> 3, h = bh & 7;
  for (int l = threadIdx.x; l < 4096; l += 256)
    cs[l >> 6][l & 63] = ctx[(size_t)bh * 4096 + l];
  __syncthreads();
  int tg = threadIdx.x >> 6, l = threadIdx.x & 63;
  for (int t = tg * 64; t < tg * 64 + 64; ++t) {
    const float* qp = qc + ((size_t)(b * TT + t)) * DD + h * 64;
    float acc = 0.f;
#pragma unroll
    for (int d2 = 0; d2 < 64; ++d2) acc += qp[d2] * cs[d2][l];
    y[((size_t)(b * TT + t)) * DD + h * 64 + l] = acc;
  }
}

// ---------------- silu elementwise ------------------------------------
__global__ __launch_bounds__(256) void silu_kernel(
    const float* __restrict__ in, float* __restrict__ out, int n) {
  int i = blockIdx.x * 256 + threadIdx.x;
  if (i < n) { float v = in[i]; out[i] = v / (1.f + __expf(-v)); }
}

// ---------------- transposes ------------------------------------------
__global__ __launch_bounds__(256) void t2b_kernel(
    const float* __restrict__ srcm, float* __restrict__ dst, int Rr) {
  int idx = blockIdx.x * 256 + threadIdx.x;
  if (idx >= Rr * BB * 128) return;
  int c4 = idx & 127;
  int row = idx >> 7;                  // b*Rr + r
  int b = row / Rr, r = row % Rr;
  ((float4*)(dst + (size_t)row * DD))[c4] =
      ((const float4*)(srcm + ((size_t)(r * BB + b)) * DD))[c4];
}
__global__ __launch_bounds__(256) void b2t_kernel(
    const float* __restrict__ xb, float* __restrict__ out) {
  int idx = blockIdx.x * 256 + threadIdx.x;
  if (idx >= TT * BB * 128) return;
  int c4 = idx & 127;
  int row = idx >> 7;                  // t*BB + b
  int t = row >> 6, b = row & 63;
  ((float4*)(out + (size_t)row * DD))[c4] =
      ((const float4*)(xb + ((size_t)(b * TT + t)) * DD))[c4];
}

extern "C" void kernel_launch(void* const* d_in, const int* in_sizes, int n_in,
                              void* d_out, int out_size, void* d_ws, size_t ws_size,
                              hipStream_t stream) {
  const float* x       = (const float*)d_in[0];
  const float* xf      = (const float*)d_in[1];
  const float* emb     = (const float*)d_in[2];
  const float* sa_in_w = (const float*)d_in[3];
  const float* sa_in_b = (const float*)d_in[4];
  const float* sa_out_w= (const float*)d_in[5];
  const float* sa_out_b= (const float*)d_in[6];
  const float* sa_l1_w = (const float*)d_in[7];
  const float* sa_l1_b = (const float*)d_in[8];
  const float* sa_l2_w = (const float*)d_in[9];
  const float* sa_l2_b = (const float*)d_in[10];
  const float* sa_n1_g = (const float*)d_in[11];
  const float* sa_n1_b = (const float*)d_in[12];
  const float* sa_n2_g = (const float*)d_in[13];
  const float* sa_n2_b = (const float*)d_in[14];
  const float* ca_norm_g = (const float*)d_in[15];
  const float* ca_norm_b = (const float*)d_in[16];
  const float* ca_tnorm_g= (const float*)d_in[17];
  const float* ca_tnorm_b= (const float*)d_in[18];
  const float* ca_q_w  = (const float*)d_in[19];
  const float* ca_q_b  = (const float*)d_in[20];
  const float* ca_k_w  = (const float*)d_in[21];
  const float* ca_k_b  = (const float*)d_in[22];
  const float* ca_v_w  = (const float*)d_in[23];
  const float* ca_v_b  = (const float*)d_in[24];
  const float* ca_se_w = (const float*)d_in[25];
  const float* ca_se_b = (const float*)d_in[26];
  const float* ca_sn_g = (const float*)d_in[27];
  const float* ca_sn_b = (const float*)d_in[28];
  const float* ca_so_w = (const float*)d_in[29];
  const float* ca_so_b = (const float*)d_in[30];
  const float* ff_l1_w = (const float*)d_in[31];
  const float* ff_l1_b = (const float*)d_in[32];
  const float* ff_l2_w = (const float*)d_in[33];
  const float* ff_l2_b = (const float*)d_in[34];
  const float* ff_se_w = (const float*)d_in[35];
  const float* ff_se_b = (const float*)d_in[36];
  const float* ff_sn_g = (const float*)d_in[37];
  const float* ff_sn_b = (const float*)d_in[38];
  const float* ff_so_w = (const float*)d_in[39];
  const float* ff_so_b = (const float*)d_in[40];

  float* R1 = (float*)d_ws;
  float* R2 = R1 + REG;
  float* R3 = R2 + REG;

  // Phase A aliases
  float* src = R1;
  unsigned short* Qbf  = (unsigned short*)R3;                 // [M1,512] bf16
  unsigned short* Obf  = (unsigned short*)(R3 + 5472256);     // [M1,512] bf16
  unsigned short* KVbf = (unsigned short*)R2;                 // [M1,1024] bf16
  float* proj  = R2;                                          // after KV dead
  unsigned short* h1bf = (unsigned short*)R2;                 // [M1,1024] bf16
  float* proj2 = R3;                                          // after Q/O dead
  // Phase B aliases
  float* xb  = R3;                      // [M2,512]
  float* tnb = R3 + 8388608;            // [BB*NN,512]
  float* xn  = R1;                      // [M2,512]
  float* kc  = R1;                      // [BB*NN,512]
  float* vc  = R1 + 2523136;
  float* ctxb= R1 + 5046272;            // [512,64,64]
  float* yb  = R2;                      // [M2,512]
  float* se  = R2 + 8388608;            // [64,512]
  float* eo  = se + 32768;              // [64,1024]
  float* eo2 = eo + 65536;              // [64,1024]
  float* qc  = (float*)d_out;           // [M2,512] scratch
  float* hst = (float*)d_out;
  // Phase C aliases
  unsigned short* g1bf = (unsigned short*)R2;   // [8192,2048] bf16 per half
  float* y2 = R1;                       // [M2,512]

  // ---------- Phase A: self-attention transformer block ----------
  concat_src_kernel<<<10688, 256, 0, stream>>>(x, xf, emb, src);
  gemm_mfma<0, false, true><<<dim3(4, 167), 256, 0, stream>>>(
      src, sa_in_w, sa_in_b, Qbf, M1, 512, 512);
  gemm_mfma<0, false, true><<<dim3(8, 167), 256, 0, stream>>>(
      src, sa_in_w + (size_t)512 * 512, sa_in_b + 512, KVbf, M1, 512, 1024);
  attn_mfma_kernel<<<dim3(6, BB * HH), 256, 0, stream>>>(Qbf, KVbf, Obf);
  gemm_mfma<0, true, false><<<dim3(4, 167), 256, 0, stream>>>(
      Obf, sa_out_w, sa_out_b, proj, M1, 512, 512);
  ln_kernel<<<M1, 64, 0, stream>>>(src, proj, src, sa_n1_g, sa_n1_b);
  gemm_mfma<1, false, true><<<dim3(8, 167), 256, 0, stream>>>(
      src, sa_l1_w, sa_l1_b, h1bf, M1, 512, 1024);
  gemm_mfma<0, true, false><<<dim3(4, 167), 256, 0, stream>>>(
      h1bf, sa_l2_w, sa_l2_b, proj2, M1, 1024, 512);
  ln_kernel<<<M1, 64, 0, stream>>>(src, proj2, src, sa_n2_g, sa_n2_b);

  // ---------- Phase B: linear cross-attention + stylization ----------
  t2b_kernel<<<8192, 256, 0, stream>>>(src, xb, TT);
  ln_kernel<<<M2, 64, 0, stream>>>(xb, nullptr, xn, ca_norm_g, ca_norm_b);
  gemm_mfma<0, false, false><<<dim3(4, 128), 256, 0, stream>>>(
      xn, ca_q_w, ca_q_b, qc, M2, 512, 512);
  softmax64_kernel<<<M2, 512, 0, stream>>>(qc);
  t2b_kernel<<<2464, 256, 0, stream>>>(xf, tnb, NN);
  ln_kernel<<<BB * NN, 64, 0, stream>>>(tnb, nullptr, tnb, ca_tnorm_g, ca_tnorm_b);
  gemm_mfma<0, false, false><<<dim3(4, 39), 256, 0, stream>>>(
      tnb, ca_k_w, ca_k_b, kc, BB * NN, 512, 512);
  softmax_n_kernel<<<dim3(64, 2), 256, 0, stream>>>(kc);
  gemm_mfma<0, false, false><<<dim3(4, 39), 256, 0, stream>>>(
      tnb, ca_v_w, ca_v_b, vc, BB * NN, 512, 512);
  ctx_kernel<<<BB * HH, 256, 0, stream>>>(kc, vc, ctxb);
  silu_kernel<<<128, 256, 0, stream>>>(emb, se, BB * DD);
  gemm_tn<0><<<dim3(16, 1), 256, 0, stream>>>(se, ca_se_w, ca_se_b, eo, BB, 1024, DD, 1024);
  gemm_tn<0><<<dim3(16, 1), 256, 0, stream>>>(se, ff_se_w, ff_se_b, eo2, BB, 1024, DD, 1024);
  lin_y_kernel<<<BB * HH, 256, 0, stream>>>(qc, ctxb, yb);
  styl_kernel<<<M2, 64, 0, stream>>>(yb, eo, ca_sn_g, ca_sn_b, hst);
  gemm_mfma<3, false, false><<<dim3(4, 128), 256, 0, stream>>>(
      hst, ca_so_w, ca_so_b, xb, M2, 512, 512);

  // ---------- Phase C: FFN + stylization (two M-halves) ----------
  for (int hlf = 0; hlf < 2; ++hlf) {
    size_t m0 = (size_t)hlf * 8192;
    gemm_mfma<2, false, true><<<dim3(16, 64), 256, 0, stream>>>(
        xb + m0 * DD, ff_l1_w, ff_l1_b, g1bf, 8192, 512, 2048);
    gemm_mfma<0, true, false><<<dim3(4, 64), 256, 0, stream>>>(
        g1bf, ff_l2_w, ff_l2_b, y2 + m0 * DD, 8192, 2048, 512);
  }
  styl_kernel<<<M2, 64, 0, stream>>>(y2, eo2, ff_sn_g, ff_sn_b, (float*)d_out);
  gemm_mfma<3, false, false><<<dim3(4, 128), 256, 0, stream>>>(
      (float*)d_out, ff_so_w, ff_so_b, xb, M2, 512, 512);

  // ---------- output transpose ----------
  b2t_kernel<<<8192, 256, 0, stream>>>(xb, (float*)d_out);
}

// Round 7
// 908.540 us; speedup vs baseline: 7.2634x; 1.2001x over previous
//
#include <hip/hip_runtime.h>
#include <hip/hip_bf16.h>
#include <cstddef>

// Problem dims
#define TT 256
#define BB 64
#define NN 77
#define DD 512
#define SS 334            // T + N + 1
#define HH 8
#define M1 (SS*BB)        // 21376
#define M2 (BB*TT)        // 16384
#define FF 2048

// Workspace: 3 regions of 10,944,512 floats each (125.25 MiB, proven OK).
#define REG 10944512ULL

typedef __attribute__((ext_vector_type(4))) float f32x4;
typedef __attribute__((ext_vector_type(8))) short bf16x8;
typedef __attribute__((ext_vector_type(8))) unsigned short u16x8;

__device__ inline unsigned short f2bf(float f) {
  __hip_bfloat16 h = __float2bfloat16(f);
  return *reinterpret_cast<unsigned short*>(&h);
}
__device__ inline float bf2f(unsigned short u) {
  return __uint_as_float(((unsigned)u) << 16);
}

// ---------------- batched f32 -> bf16 weight converter -----------------
__global__ __launch_bounds__(256) void cvt4_kernel(
    const float* s0, unsigned short* d0, int n0,
    const float* s1, unsigned short* d1, int n1,
    const float* s2, unsigned short* d2, int n2,
    const float* s3, unsigned short* d3, int n3) {
  const float* s; unsigned short* d; int n;
  switch (blockIdx.y) {
    case 0: s = s0; d = d0; n = n0; break;
    case 1: s = s1; d = d1; n = n1; break;
    case 2: s = s2; d = d2; n = n2; break;
    default: s = s3; d = d3; n = n3; break;
  }
  for (int i = (blockIdx.x * 256 + threadIdx.x) * 4; i < n; i += gridDim.x * 1024) {
    float4 v = *(const float4*)(s + i);
    ushort4 u;
    u.x = f2bf(v.x); u.y = f2bf(v.y); u.z = f2bf(v.z); u.w = f2bf(v.w);
    *(ushort4*)(d + i) = u;
  }
}

// ---------------- concat [x; xf; emb] -> src f32 + bf16 ----------------
__global__ __launch_bounds__(256) void concat_src_kernel(
    const float* __restrict__ x, const float* __restrict__ xf,
    const float* __restrict__ emb, float* __restrict__ src,
    unsigned short* __restrict__ srcbf) {
  int idx = blockIdx.x * 256 + threadIdx.x;      // float4 index
  if (idx >= SS * BB * 128) return;
  int c4 = idx & 127;
  int row = idx >> 7;                            // s*BB + b
  int s = row >> 6, b = row & 63;
  const float* p;
  if (s < TT)            p = x   + ((size_t)(s * BB + b)) * DD;
  else if (s < TT + NN)  p = xf  + ((size_t)((s - TT) * BB + b)) * DD;
  else                   p = emb + (size_t)b * DD;
  float4 v = ((const float4*)p)[c4];
  ((float4*)(src + (size_t)row * DD))[c4] = v;
  ushort4 u;
  u.x = f2bf(v.x); u.y = f2bf(v.y); u.z = f2bf(v.z); u.w = f2bf(v.w);
  ((ushort4*)(srcbf + (size_t)row * DD))[c4] = u;
}

// ---------------- MFMA GEMM (all-bf16 operands) ------------------------
// C = epi(A[M,K]bf16 @ W[N,K]bf16^T + bias); 128x128 tile, 4 waves, BK=32.
// EPI: 0 none, 1 relu, 2 gelu, 3 add-into-C(f32),
//      4 add-into-C(f32) + write bf16 copy to C2,
//      5 out = C(f32 read) + v, write f32 TRANSPOSED (row=b*TT+t -> t*BB+b) to C2.
// CBF: write bf16 output (EPI 0-2 only).
template<int EPI, bool CBF>
__global__ __launch_bounds__(256) void gemm_bf(
    const unsigned short* __restrict__ A, const unsigned short* __restrict__ W,
    const float* __restrict__ bias, void* __restrict__ Cp_, void* __restrict__ C2,
    int M, int K, int ldc) {
  __shared__ unsigned short As[4][128][8];   // [k-chunk][row][k-in-chunk]
  __shared__ unsigned short Bs[4][128][8];
  const int tid = threadIdx.x;
  const int bm = blockIdx.y * 128;
  const int bn = blockIdx.x * 128;
  const int lane = tid & 63;
  const int wave = tid >> 6;
  const int wr = wave >> 1, wc = wave & 1;
  const int q = lane >> 4, lr = lane & 15;

  f32x4 acc[4][4];
#pragma unroll
  for (int m = 0; m < 4; ++m)
#pragma unroll
    for (int n = 0; n < 4; ++n) acc[m][n] = (f32x4){0.f, 0.f, 0.f, 0.f};

  const int srow = tid >> 1;
  const int skc = (tid & 1) * 16;
  const int c0 = (tid & 1) * 2;
  int arow = bm + srow; if (arow >= M) arow = M - 1;
  const unsigned short* Ab = A + (size_t)arow * K + skc;
  const unsigned short* Wb = W + (size_t)(bn + srow) * K + skc;

  for (int k0 = 0; k0 < K; k0 += 32) {
    u16x8 av0 = *(const u16x8*)(Ab + k0);
    u16x8 av1 = *(const u16x8*)(Ab + k0 + 8);
    u16x8 bv0 = *(const u16x8*)(Wb + k0);
    u16x8 bv1 = *(const u16x8*)(Wb + k0 + 8);
    __syncthreads();
    *(u16x8*)&As[c0][srow][0] = av0;
    *(u16x8*)&As[c0 + 1][srow][0] = av1;
    *(u16x8*)&Bs[c0][srow][0] = bv0;
    *(u16x8*)&Bs[c0 + 1][srow][0] = bv1;
    __syncthreads();
    bf16x8 af[4], bf[4];
#pragma unroll
    for (int m = 0; m < 4; ++m) af[m] = *(const bf16x8*)&As[q][wr * 64 + m * 16 + lr][0];
#pragma unroll
    for (int n = 0; n < 4; ++n) bf[n] = *(const bf16x8*)&Bs[q][wc * 64 + n * 16 + lr][0];
#pragma unroll
    for (int m = 0; m < 4; ++m)
#pragma unroll
      for (int n = 0; n < 4; ++n)
        acc[m][n] = __builtin_amdgcn_mfma_f32_16x16x32_bf16(af[m], bf[n], acc[m][n], 0, 0, 0);
  }

#pragma unroll
  for (int m = 0; m < 4; ++m) {
#pragma unroll
    for (int n = 0; n < 4; ++n) {
      const int col = bn + wc * 64 + n * 16 + lr;
      const float bb = bias[col];
#pragma unroll
      for (int i = 0; i < 4; ++i) {
        const int row = bm + wr * 64 + m * 16 + q * 4 + i;
        if (row < M) {
          float v = acc[m][n][i] + bb;
          if (EPI == 1) v = fmaxf(v, 0.f);
          if (EPI == 2) v = 0.5f * v * (1.f + erff(v * 0.70710678118f));
          if (EPI <= 2) {
            if (CBF) ((unsigned short*)Cp_)[(size_t)row * ldc + col] = f2bf(v);
            else     ((float*)Cp_)[(size_t)row * ldc + col] = v;
          } else if (EPI == 3) {
            ((float*)Cp_)[(size_t)row * ldc + col] += v;
          } else if (EPI == 4) {
            float* C = (float*)Cp_ + (size_t)row * ldc + col;
            float o = *C + v; *C = o;
            ((unsigned short*)C2)[(size_t)row * ldc + col] = f2bf(o);
          } else {  // EPI == 5
            float o = ((const float*)Cp_)[(size_t)row * ldc + col] + v;
            int t = row & 255, b2 = row >> 8;
            ((float*)C2)[((size_t)(t * BB + b2)) * DD + col] = o;
          }
        }
      }
    }
  }
}

// ---------------- MFMA flash attention (unchanged, proven) -------------
__global__ __launch_bounds__(256) void attn_mfma_kernel(
    const unsigned short* __restrict__ Qb, const unsigned short* __restrict__ KVb,
    unsigned short* __restrict__ Ob) {
  __shared__ unsigned short Qs[64][72];
  __shared__ unsigned short Ks[64][72];
  __shared__ unsigned short Vt[64][72];
  __shared__ unsigned short Ps[4][16][72];
  const int bh = blockIdx.y, b = bh >> 3, h = bh & 7;
  const int s0 = blockIdx.x << 6;
  const int tid = threadIdx.x;
  const int wave = tid >> 6, lane = tid & 63;
  const int q = lane >> 4, lr = lane & 15;
  const int sr = tid >> 2;
  const int c0 = (tid & 3) << 4;
  {
    int s = s0 + sr;
    u16x8 v0 = {0, 0, 0, 0, 0, 0, 0, 0}, v1 = v0;
    if (s < SS) {
      const unsigned short* qp = Qb + ((size_t)(s * BB + b)) * 512 + h * 64 + c0;
      v0 = *(const u16x8*)qp; v1 = *(const u16x8*)(qp + 8);
    }
    *(u16x8*)&Qs[sr][c0] = v0;
    *(u16x8*)&Qs[sr][c0 + 8] = v1;
  }
  f32x4 oacc[4];
#pragma unroll
  for (int dt = 0; dt < 4; ++dt) oacc[dt] = (f32x4){0.f, 0.f, 0.f, 0.f};
  float m_r[4] = {-1e30f, -1e30f, -1e30f, -1e30f};
  float l_r[4] = {0.f, 0.f, 0.f, 0.f};
  for (int kt = 0; kt < 6; ++kt) {
    __syncthreads();
    {
      int t = kt * 64 + sr;
      u16x8 k0 = {0, 0, 0, 0, 0, 0, 0, 0}, k1 = k0, w0 = k0, w1 = k0;
      if (t < SS) {
        const unsigned short* kp = KVb + ((size_t)(t * BB + b)) * 1024 + h * 64 + c0;
        k0 = *(const u16x8*)kp; k1 = *(const u16x8*)(kp + 8);
        w0 = *(const u16x8*)(kp + 512); w1 = *(const u16x8*)(kp + 520);
      }
      *(u16x8*)&Ks[sr][c0] = k0;
      *(u16x8*)&Ks[sr][c0 + 8] = k1;
#pragma unroll
      for (int j = 0; j < 8; ++j) Vt[c0 + j][sr] = w0[j];
#pragma unroll
      for (int j = 0; j < 8; ++j) Vt[c0 + 8 + j][sr] = w1[j];
    }
    __syncthreads();
    f32x4 sacc[4];
#pragma unroll
    for (int ct = 0; ct < 4; ++ct) sacc[ct] = (f32x4){0.f, 0.f, 0.f, 0.f};
#pragma unroll
    for (int kc = 0; kc < 2; ++kc) {
      bf16x8 aq = *(const bf16x8*)&Qs[wave * 16 + lr][kc * 32 + q * 8];
#pragma unroll
      for (int ct = 0; ct < 4; ++ct) {
        bf16x8 bk = *(const bf16x8*)&Ks[ct * 16 + lr][kc * 32 + q * 8];
        sacc[ct] = __builtin_amdgcn_mfma_f32_16x16x32_bf16(aq, bk, sacc[ct], 0, 0, 0);
      }
    }
    float pexp[4][4];
#pragma unroll
    for (int i = 0; i < 4; ++i) {
      float mt = -1e30f;
#pragma unroll
      for (int ct = 0; ct < 4; ++ct) {
        float sv = sacc[ct][i] * 0.125f;
        if (kt * 64 + ct * 16 + lr >= SS) sv = -1e30f;
        sacc[ct][i] = sv;
        mt = fmaxf(mt, sv);
      }
#pragma unroll
      for (int off = 8; off; off >>= 1) mt = fmaxf(mt, __shfl_xor(mt, off));
      float mn = fmaxf(m_r[i], mt);
      float rescale = __expf(m_r[i] - mn);
      m_r[i] = mn;
      float se = 0.f;
#pragma unroll
      for (int ct = 0; ct < 4; ++ct) {
        float e = __expf(sacc[ct][i] - mn);
        pexp[ct][i] = e;
        se += e;
      }
#pragma unroll
      for (int off = 8; off; off >>= 1) se += __shfl_xor(se, off);
      l_r[i] = l_r[i] * rescale + se;
#pragma unroll
      for (int dt = 0; dt < 4; ++dt) oacc[dt][i] *= rescale;
    }
#pragma unroll
    for (int ct = 0; ct < 4; ++ct)
#pragma unroll
      for (int i = 0; i < 4; ++i)
        Ps[wave][q * 4 + i][ct * 16 + lr] = f2bf(pexp[ct][i]);
#pragma unroll
    for (int kc = 0; kc < 2; ++kc) {
      bf16x8 ap = *(const bf16x8*)&Ps[wave][lr][kc * 32 + q * 8];
#pragma unroll
      for (int dt = 0; dt < 4; ++dt) {
        bf16x8 bv = *(const bf16x8*)&Vt[dt * 16 + lr][kc * 32 + q * 8];
        oacc[dt] = __builtin_amdgcn_mfma_f32_16x16x32_bf16(ap, bv, oacc[dt], 0, 0, 0);
      }
    }
  }
#pragma unroll
  for (int i = 0; i < 4; ++i) {
    int s = s0 + wave * 16 + q * 4 + i;
    if (s < SS) {
      float inv = 1.f / l_r[i];
      unsigned short* op = Ob + ((size_t)(s * BB + b)) * 512 + h * 64;
#pragma unroll
      for (int dt = 0; dt < 4; ++dt)
        op[dt * 16 + lr] = f2bf(oacc[dt][i] * inv);
    }
  }
}

// ---------------- small VALU GEMM (M=64: stylization emb linears) ------
template<int EPI>
__global__ __launch_bounds__(256) void gemm_tn(
    const float* __restrict__ A, const float* __restrict__ W,
    const float* __restrict__ bias, float* __restrict__ C,
    int M, int N, int K, int ldc) {
  __shared__ float As[16][64];
  __shared__ float Ws[16][64];
  const int tid = threadIdx.x;
  const int bm = blockIdx.y << 6;
  const int bn = blockIdx.x << 6;
  const int lr = tid >> 2;
  const int lk = (tid & 3) << 2;
  const float* Ap = A + (size_t)(bm + lr) * K + lk;
  const float* Wp = W + (size_t)(bn + lr) * K + lk;
  const int tx = tid & 15, ty = tid >> 4;
  float c[4][4] = {};
  for (int k0 = 0; k0 < K; k0 += 16) {
    float4 av = *(const float4*)(Ap + k0);
    float4 wv = *(const float4*)(Wp + k0);
    __syncthreads();
    As[lk + 0][lr] = av.x; As[lk + 1][lr] = av.y;
    As[lk + 2][lr] = av.z; As[lk + 3][lr] = av.w;
    Ws[lk + 0][lr] = wv.x; Ws[lk + 1][lr] = wv.y;
    Ws[lk + 2][lr] = wv.z; Ws[lk + 3][lr] = wv.w;
    __syncthreads();
#pragma unroll
    for (int k = 0; k < 16; ++k) {
      const float4 a = *(const float4*)&As[k][ty << 2];
      const float4 w = *(const float4*)&Ws[k][tx << 2];
      c[0][0] += a.x * w.x; c[0][1] += a.x * w.y; c[0][2] += a.x * w.z; c[0][3] += a.x * w.w;
      c[1][0] += a.y * w.x; c[1][1] += a.y * w.y; c[1][2] += a.y * w.z; c[1][3] += a.y * w.w;
      c[2][0] += a.z * w.x; c[2][1] += a.z * w.y; c[2][2] += a.z * w.z; c[2][3] += a.z * w.w;
      c[3][0] += a.w * w.x; c[3][1] += a.w * w.y; c[3][2] += a.w * w.z; c[3][3] += a.w * w.w;
    }
  }
#pragma unroll
  for (int i = 0; i < 4; ++i) {
    int row = bm + (ty << 2) + i;
    float* Cp = C + (size_t)row * ldc + bn + (tx << 2);
#pragma unroll
    for (int j = 0; j < 4; ++j) {
      float v = c[i][j] + bias[bn + (tx << 2) + j];
      if (EPI == 1) v = fmaxf(v, 0.f);
      if (EPI == 3) Cp[j] += v; else Cp[j] = v;
    }
  }
}

// ---------------- LayerNorm row kernel: f32 out + optional bf16 out ----
__global__ __launch_bounds__(64) void ln_kernel(
    const float* __restrict__ in, const float* __restrict__ res,
    float* __restrict__ out, const float* __restrict__ g,
    const float* __restrict__ beta, unsigned short* __restrict__ obf) {
  const int row = blockIdx.x;
  const int lane = threadIdx.x;
  const float* ip = in + (size_t)row * DD;
  float v[8];
  float s = 0.f, ss = 0.f;
#pragma unroll
  for (int u = 0; u < 2; ++u) {
    int d = u * 256 + lane * 4;
    float4 a = *(const float4*)(ip + d);
    if (res) {
      float4 r = *(const float4*)(res + (size_t)row * DD + d);
      a.x += r.x; a.y += r.y; a.z += r.z; a.w += r.w;
    }
    v[u * 4 + 0] = a.x; v[u * 4 + 1] = a.y; v[u * 4 + 2] = a.z; v[u * 4 + 3] = a.w;
    s += a.x + a.y + a.z + a.w;
    ss += a.x * a.x + a.y * a.y + a.z * a.z + a.w * a.w;
  }
#pragma unroll
  for (int off = 32; off; off >>= 1) { s += __shfl_xor(s, off); ss += __shfl_xor(ss, off); }
  float mean = s * (1.f / 512.f);
  float var = ss * (1.f / 512.f) - mean * mean;
  float rstd = rsqrtf(var + 1e-5f);
  float* op = out + (size_t)row * DD;
#pragma unroll
  for (int u = 0; u < 2; ++u) {
    int d = u * 256 + lane * 4;
    float4 o4;
    o4.x = (v[u * 4 + 0] - mean) * rstd * g[d + 0] + beta[d + 0];
    o4.y = (v[u * 4 + 1] - mean) * rstd * g[d + 1] + beta[d + 1];
    o4.z = (v[u * 4 + 2] - mean) * rstd * g[d + 2] + beta[d + 2];
    o4.w = (v[u * 4 + 3] - mean) * rstd * g[d + 3] + beta[d + 3];
    *(float4*)(op + d) = o4;
    if (obf) {
      ushort4 u4;
      u4.x = f2bf(o4.x); u4.y = f2bf(o4.y); u4.z = f2bf(o4.z); u4.w = f2bf(o4.w);
      *(ushort4*)(obf + (size_t)row * DD + d) = u4;
    }
  }
}

// ------- fused transpose + LN: out row rp=b*Rr+r <- in row r*BB+b -------
// writes raw transposed f32 (if WF32) and LN'd bf16.
template<bool WF32>
__global__ __launch_bounds__(64) void t2bln_kernel(
    const float* __restrict__ in, float* __restrict__ raw,
    unsigned short* __restrict__ obf, const float* __restrict__ g,
    const float* __restrict__ beta, int Rr) {
  const int rp = blockIdx.x;
  const int b = rp / Rr, r = rp % Rr;
  const float* ip = in + ((size_t)(r * BB + b)) * DD;
  const int lane = threadIdx.x;
  float v[8];
  float s = 0.f, ss = 0.f;
#pragma unroll
  for (int u = 0; u < 2; ++u) {
    int d = u * 256 + lane * 4;
    float4 a = *(const float4*)(ip + d);
    if (WF32) *(float4*)(raw + (size_t)rp * DD + d) = a;
    v[u * 4 + 0] = a.x; v[u * 4 + 1] = a.y; v[u * 4 + 2] = a.z; v[u * 4 + 3] = a.w;
    s += a.x + a.y + a.z + a.w;
    ss += a.x * a.x + a.y * a.y + a.z * a.z + a.w * a.w;
  }
#pragma unroll
  for (int off = 32; off; off >>= 1) { s += __shfl_xor(s, off); ss += __shfl_xor(ss, off); }
  float mean = s * (1.f / 512.f);
  float var = ss * (1.f / 512.f) - mean * mean;
  float rstd = rsqrtf(var + 1e-5f);
#pragma unroll
  for (int u = 0; u < 2; ++u) {
    int d = u * 256 + lane * 4;
    ushort4 u4;
    u4.x = f2bf((v[u * 4 + 0] - mean) * rstd * g[d + 0] + beta[d + 0]);
    u4.y = f2bf((v[u * 4 + 1] - mean) * rstd * g[d + 1] + beta[d + 1]);
    u4.z = f2bf((v[u * 4 + 2] - mean) * rstd * g[d + 2] + beta[d + 2]);
    u4.w = f2bf((v[u * 4 + 3] - mean) * rstd * g[d + 3] + beta[d + 3]);
    *(ushort4*)(obf + (size_t)rp * DD + d) = u4;
  }
}

// ---------------- stylization: silu(LN(y)*(1+scale)+shift) -> bf16 -----
__global__ __launch_bounds__(64) void styl_kernel(
    const float* __restrict__ y, const float* __restrict__ eo,
    const float* __restrict__ g, const float* __restrict__ beta,
    unsigned short* __restrict__ out) {
  const int row = blockIdx.x;         // b*TT + t
  const int b = row >> 8;
  const int lane = threadIdx.x;
  const float* ip = y + (size_t)row * DD;
  const float* sc = eo + (size_t)b * 1024;
  float v[8];
  float s = 0.f, ss = 0.f;
#pragma unroll
  for (int u = 0; u < 2; ++u) {
    int d = u * 256 + lane * 4;
    float4 a = *(const float4*)(ip + d);
    v[u * 4 + 0] = a.x; v[u * 4 + 1] = a.y; v[u * 4 + 2] = a.z; v[u * 4 + 3] = a.w;
    s += a.x + a.y + a.z + a.w;
    ss += a.x * a.x + a.y * a.y + a.z * a.z + a.w * a.w;
  }
#pragma unroll
  for (int off = 32; off; off >>= 1) { s += __shfl_xor(s, off); ss += __shfl_xor(ss, off); }
  float mean = s * (1.f / 512.f);
  float var = ss * (1.f / 512.f) - mean * mean;
  float rstd = rsqrtf(var + 1e-5f);
#pragma unroll
  for (int u = 0; u < 2; ++u) {
    int d0 = u * 256 + lane * 4;
    ushort4 u4;
#pragma unroll
    for (int j = 0; j < 4; ++j) {
      int d = d0 + j;
      float ln = (v[u * 4 + j] - mean) * rstd * g[d] + beta[d];
      float h = ln * (1.f + sc[d]) + sc[512 + d];
      float r = h / (1.f + __expf(-h));
      ((unsigned short*)&u4)[j] = f2bf(r);
    }
    *(ushort4*)(out + (size_t)row * DD + d0) = u4;
  }
}

// ---------------- per-64-group softmax (qc, last axis) -----------------
__global__ __launch_bounds__(512) void softmax64_kernel(float* __restrict__ a) {
  int row = blockIdx.x;
  int lane = threadIdx.x & 63;
  int h = threadIdx.x >> 6;
  float* p = a + (size_t)row * DD + h * 64;
  float v = p[lane];
  float m = v;
#pragma unroll
  for (int off = 32; off; off >>= 1) m = fmaxf(m, __shfl_xor(m, off));
  float e = __expf(v - m);
  float sum = e;
#pragma unroll
  for (int off = 32; off; off >>= 1) sum += __shfl_xor(sum, off);
  p[lane] = e / sum;
}

// ---------------- softmax over n (kc, axis=1, 77 tokens) ---------------
__global__ __launch_bounds__(256) void softmax_n_kernel(float* __restrict__ a) {
  int b = blockIdx.x;
  int c = blockIdx.y * 256 + threadIdx.x;
  float* p = a + ((size_t)b * NN) * DD + c;
  float m = -1e30f;
  for (int n = 0; n < NN; ++n) m = fmaxf(m, p[(size_t)n * DD]);
  float sum = 0.f;
  for (int n = 0; n < NN; ++n) sum += __expf(p[(size_t)n * DD] - m);
  float inv = 1.f / sum;
  for (int n = 0; n < NN; ++n) p[(size_t)n * DD] = __expf(p[(size_t)n * DD] - m) * inv;
}

// ---------------- ctx[b,h,d,l] = sum_n kc[b,n,h,d]*vc[b,n,h,l] ---------
__global__ __launch_bounds__(256) void ctx_kernel(
    const float* __restrict__ kc, const float* __restrict__ vc,
    float* __restrict__ ctx) {
  __shared__ float ks[NN][64];
  __shared__ float vs[NN][64];
  int bh = blockIdx.x; int b = bh >> 3, h = bh & 7;
  for (int l = threadIdx.x; l < NN * 64; l += 256) {
    int n = l >> 6, d = l & 63;
    size_t idx = ((size_t)(b * NN + n)) * DD + h * 64 + d;
    ks[n][d] = kc[idx];
    vs[n][d] = vc[idx];
  }
  __syncthreads();
  int d = threadIdx.x >> 2;
  int l0 = (threadIdx.x & 3) << 4;
  float acc[16] = {};
  for (int n = 0; n < NN; ++n) {
    float kd = ks[n][d];
#pragma unroll
    for (int j = 0; j < 16; ++j) acc[j] += kd * vs[n][l0 + j];
  }
  float* cp = ctx + ((size_t)bh * 64 + d) * 64 + l0;
#pragma unroll
  for (int j = 0; j < 16; ++j) cp[j] = acc[j];
}

// ---------------- y[b,t,h,l] = sum_d qc[b,t,h,d]*ctx[b,h,d,l] ----------
__global__ __launch_bounds__(256) void lin_y_kernel(
    const float* __restrict__ qc, const float* __restrict__ ctx,
    float* __restrict__ y) {
  __shared__ float cs[64][64];
  int bh = blockIdx.x; int b = bh >> 3, h = bh & 7;
  for (int l = threadIdx.x; l < 4096; l += 256)
    cs[l >> 6][l & 63] = ctx[(size_t)bh * 4096 + l];
  __syncthreads();
  int tg = threadIdx.x >> 6, l = threadIdx.x & 63;
  for (int t = tg * 64; t < tg * 64 + 64; ++t) {
    const float* qp = qc + ((size_t)(b * TT + t)) * DD + h * 64;
    float acc = 0.f;
#pragma unroll
    for (int d2 = 0; d2 < 64; ++d2) acc += qp[d2] * cs[d2][l];
    y[((size_t)(b * TT + t)) * DD + h * 64 + l] = acc;
  }
}

// ---------------- silu elementwise ------------------------------------
__global__ __launch_bounds__(256) void silu_kernel(
    const float* __restrict__ in, float* __restrict__ out, int n) {
  int i = blockIdx.x * 256 + threadIdx.x;
  if (i < n) { float v = in[i]; out[i] = v / (1.f + __expf(-v)); }
}

extern "C" void kernel_launch(void* const* d_in, const int* in_sizes, int n_in,
                              void* d_out, int out_size, void* d_ws, size_t ws_size,
                              hipStream_t stream) {
  const float* x       = (const float*)d_in[0];
  const float* xf      = (const float*)d_in[1];
  const float* emb     = (const float*)d_in[2];
  const float* sa_in_w = (const float*)d_in[3];
  const float* sa_in_b = (const float*)d_in[4];
  const float* sa_out_w= (const float*)d_in[5];
  const float* sa_out_b= (const float*)d_in[6];
  const float* sa_l1_w = (const float*)d_in[7];
  const float* sa_l1_b = (const float*)d_in[8];
  const float* sa_l2_w = (const float*)d_in[9];
  const float* sa_l2_b = (const float*)d_in[10];
  const float* sa_n1_g = (const float*)d_in[11];
  const float* sa_n1_b = (const float*)d_in[12];
  const float* sa_n2_g = (const float*)d_in[13];
  const float* sa_n2_b = (const float*)d_in[14];
  const float* ca_norm_g = (const float*)d_in[15];
  const float* ca_norm_b = (const float*)d_in[16];
  const float* ca_tnorm_g= (const float*)d_in[17];
  const float* ca_tnorm_b= (const float*)d_in[18];
  const float* ca_q_w  = (const float*)d_in[19];
  const float* ca_q_b  = (const float*)d_in[20];
  const float* ca_k_w  = (const float*)d_in[21];
  const float* ca_k_b  = (const float*)d_in[22];
  const float* ca_v_w  = (const float*)d_in[23];
  const float* ca_v_b  = (const float*)d_in[24];
  const float* ca_se_w = (const float*)d_in[25];
  const float* ca_se_b = (const float*)d_in[26];
  const float* ca_sn_g = (const float*)d_in[27];
  const float* ca_sn_b = (const float*)d_in[28];
  const float* ca_so_w = (const float*)d_in[29];
  const float* ca_so_b = (const float*)d_in[30];
  const float* ff_l1_w = (const float*)d_in[31];
  const float* ff_l1_b = (const float*)d_in[32];
  const float* ff_l2_w = (const float*)d_in[33];
  const float* ff_l2_b = (const float*)d_in[34];
  const float* ff_se_w = (const float*)d_in[35];
  const float* ff_se_b = (const float*)d_in[36];
  const float* ff_sn_g = (const float*)d_in[37];
  const float* ff_sn_b = (const float*)d_in[38];
  const float* ff_so_w = (const float*)d_in[39];
  const float* ff_so_b = (const float*)d_in[40];

  float* R1 = (float*)d_ws;
  float* R2 = R1 + REG;
  float* R3 = R2 + REG;
  float* dof = (float*)d_out;          // 8,388,608 floats of scratch until the end

  // bf16 weight slots
  unsigned short* w_sa_in  = (unsigned short*)dof;            // 786432
  unsigned short* w_sa_out = w_sa_in + 786432;                // 262144
  unsigned short* w_sa_l1  = w_sa_out + 262144;               // 524288
  unsigned short* w_sa_l2  = w_sa_l1 + 524288;                // 524288 (tot 1,048,576 fl)
  unsigned short* srcbf    = (unsigned short*)(dof + 1048576);// [M1,512] -> ends 6,520,832 fl
  unsigned short* w_ca_q  = (unsigned short*)(R2 + 8552448);  // 262144 each
  unsigned short* w_ca_k  = w_ca_q + 262144;
  unsigned short* w_ca_v  = w_ca_k + 262144;
  unsigned short* w_ca_so = w_ca_v + 262144;                  // ends 9,076,736 fl
  unsigned short* w_ff_l1 = (unsigned short*)(R2 + 9076736);  // 1,048,576
  unsigned short* w_ff_l2 = w_ff_l1 + 1048576;                // 1,048,576
  unsigned short* w_ff_so = w_ff_l2 + 1048576;                // 262144 -> ends 10,256,384 fl

  // Phase A aliases
  float* src = R1;
  unsigned short* Qbf  = (unsigned short*)R3;                 // [M1,512]
  unsigned short* Obf  = (unsigned short*)(R3 + 5472256);     // [M1,512]
  unsigned short* KVbf = (unsigned short*)R2;                 // [M1,1024]
  float* proj  = R2;
  unsigned short* h1bf = (unsigned short*)R2;                 // [M1,1024]
  float* proj2 = R3;
  // Phase B aliases
  float* xb = R3;                                             // [M2,512] f32
  unsigned short* xnbf = (unsigned short*)R2;                 // [M2,512]
  unsigned short* tnbf = (unsigned short*)(R2 + 4194304);     // [4928,512]
  float* qc  = dof;                                           // [M2,512]
  float* kc  = R1;
  float* vc  = R1 + 2523136;
  float* ctxb= R1 + 5046272;                                  // [512,64,64]
  float* se  = R2 + 8388608;                                  // [64,512]
  float* eo  = se + 32768;                                    // [64,1024]
  float* eo2 = eo + 65536;                                    // [64,1024] ends 8,552,448
  float* yb  = R2;                                            // [M2,512]
  unsigned short* hstbf = (unsigned short*)R1;                // [M2,512]
  unsigned short* xbbf  = (unsigned short*)(R1 + 4194304);    // [M2,512]
  // Phase C aliases
  unsigned short* g1bf = (unsigned short*)R2;                 // [8192,2048]
  float* y2 = R1;                                             // [M2,512]
  unsigned short* hst2bf = (unsigned short*)R2;               // [M2,512]

  // ---------- Phase A ----------
  cvt4_kernel<<<dim3(1024, 4), 256, 0, stream>>>(
      sa_in_w, w_sa_in, 786432, sa_out_w, w_sa_out, 262144,
      sa_l1_w, w_sa_l1, 524288, sa_l2_w, w_sa_l2, 524288);
  concat_src_kernel<<<10688, 256, 0, stream>>>(x, xf, emb, src, srcbf);
  gemm_bf<0, true><<<dim3(4, 167), 256, 0, stream>>>(
      srcbf, w_sa_in, sa_in_b, Qbf, nullptr, M1, 512, 512);
  gemm_bf<0, true><<<dim3(8, 167), 256, 0, stream>>>(
      srcbf, w_sa_in + (size_t)512 * 512, sa_in_b + 512, KVbf, nullptr, M1, 512, 1024);
  attn_mfma_kernel<<<dim3(6, BB * HH), 256, 0, stream>>>(Qbf, KVbf, Obf);
  gemm_bf<0, false><<<dim3(4, 167), 256, 0, stream>>>(
      Obf, w_sa_out, sa_out_b, proj, nullptr, M1, 512, 512);
  ln_kernel<<<M1, 64, 0, stream>>>(src, proj, src, sa_n1_g, sa_n1_b, srcbf);
  gemm_bf<1, true><<<dim3(8, 167), 256, 0, stream>>>(
      srcbf, w_sa_l1, sa_l1_b, h1bf, nullptr, M1, 512, 1024);
  gemm_bf<0, false><<<dim3(4, 167), 256, 0, stream>>>(
      h1bf, w_sa_l2, sa_l2_b, proj2, nullptr, M1, 1024, 512);
  // ca/ff weight conversion (R2 slack free after h1bf consumed)
  cvt4_kernel<<<dim3(1024, 4), 256, 0, stream>>>(
      ca_q_w, w_ca_q, 262144, ca_k_w, w_ca_k, 262144,
      ca_v_w, w_ca_v, 262144, ca_so_w, w_ca_so, 262144);
  cvt4_kernel<<<dim3(1024, 4), 256, 0, stream>>>(
      ff_l1_w, w_ff_l1, 1048576, ff_l2_w, w_ff_l2, 1048576,
      ff_so_w, w_ff_so, 262144, nullptr, nullptr, 0);
  ln_kernel<<<M1, 64, 0, stream>>>(src, proj2, src, sa_n2_g, sa_n2_b, nullptr);

  // ---------- Phase B ----------
  t2bln_kernel<true><<<M2, 64, 0, stream>>>(src, xb, xnbf, ca_norm_g, ca_norm_b, TT);
  gemm_bf<0, false><<<dim3(4, 128), 256, 0, stream>>>(
      xnbf, w_ca_q, ca_q_b, qc, nullptr, M2, 512, 512);
  softmax64_kernel<<<M2, 512, 0, stream>>>(qc);
  t2bln_kernel<false><<<BB * NN, 64, 0, stream>>>(xf, nullptr, tnbf, ca_tnorm_g, ca_tnorm_b, NN);
  gemm_bf<0, false><<<dim3(4, 39), 256, 0, stream>>>(
      tnbf, w_ca_k, ca_k_b, kc, nullptr, BB * NN, 512, 512);
  softmax_n_kernel<<<dim3(64, 2), 256, 0, stream>>>(kc);
  gemm_bf<0, false><<<dim3(4, 39), 256, 0, stream>>>(
      tnbf, w_ca_v, ca_v_b, vc, nullptr, BB * NN, 512, 512);
  ctx_kernel<<<BB * HH, 256, 0, stream>>>(kc, vc, ctxb);
  silu_kernel<<<128, 256, 0, stream>>>(emb, se, BB * DD);
  gemm_tn<0><<<dim3(16, 1), 256, 0, stream>>>(se, ca_se_w, ca_se_b, eo, BB, 1024, DD, 1024);
  gemm_tn<0><<<dim3(16, 1), 256, 0, stream>>>(se, ff_se_w, ff_se_b, eo2, BB, 1024, DD, 1024);
  lin_y_kernel<<<BB * HH, 256, 0, stream>>>(qc, ctxb, yb);
  styl_kernel<<<M2, 64, 0, stream>>>(yb, eo, ca_sn_g, ca_sn_b, hstbf);
  gemm_bf<4, false><<<dim3(4, 128), 256, 0, stream>>>(
      hstbf, w_ca_so, ca_so_b, xb, xbbf, M2, 512, 512);

  // ---------- Phase C (two M-halves) ----------
  for (int hlf = 0; hlf < 2; ++hlf) {
    size_t m0 = (size_t)hlf * 8192;
    gemm_bf<2, true><<<dim3(16, 64), 256, 0, stream>>>(
        xbbf + m0 * DD, w_ff_l1, ff_l1_b, g1bf, nullptr, 8192, 512, 2048);
    gemm_bf<0, false><<<dim3(4, 64), 256, 0, stream>>>(
        g1bf, w_ff_l2, ff_l2_b, y2 + m0 * DD, nullptr, 8192, 2048, 512);
  }
  styl_kernel<<<M2, 64, 0, stream>>>(y2, eo2, ff_sn_g, ff_sn_b, hst2bf);
  // final: out = transpose(xb + hst2 @ ff_so^T + bias)
  gemm_bf<5, false><<<dim3(4, 128), 256, 0, stream>>>(
      hst2bf, w_ff_so, ff_so_b, xb, dof, M2, 512, 512);
}